// Round 21
// baseline (226.348 us; speedup 1.0000x reference)
//
#include <hip/hip_runtime.h>

#define TT 256
#define BB 512
#define DD 128
#define HH 50
#define KK 5
#define AA 4
#define NROW 131072

typedef _Float16 half4 __attribute__((ext_vector_type(4)));
typedef float f32x4 __attribute__((ext_vector_type(4)));

// ---------------- K0: weight prep ----------------
__global__ void k0_prep(const float* __restrict__ W_in,
                        const float* __restrict__ W_ctx,
                        const float* __restrict__ W_key,
                        const float* __restrict__ W_q,
                        const float* __restrict__ b_key,
                        const float* __restrict__ b_q,
                        float* __restrict__ WHT,
                        float* __restrict__ WK2T, float* __restrict__ bias2) {
  int i = blockIdx.x * 256 + threadIdx.x;
  if (i < HH * 52) {
    int j = i / 52, h = i % 52;
    WHT[i] = (h < HH) ? W_ctx[h * (2 * HH) + HH + j] : 0.f;
  }
  if (i < HH * 64) {
    int j = i >> 6, l = i & 63;
    float v = 0.f;
    if (l < HH) v = W_ctx[l * (2 * HH) + j];
    else if (l < HH + KK) v = W_key[(l - HH) * HH + j];
    else if (l < HH + 2 * KK) v = W_q[(l - HH - KK) * HH + j];
    WK2T[i] = v;
  }
  if (i < 64) {
    float bv = 0.f;
    if (i >= HH && i < HH + KK) bv = b_key[i - HH];
    else if (i >= HH + KK && i < HH + 2 * KK) bv = b_q[i - HH - KK];
    bias2[i] = bv;
  }
}

// ---------------- K1 (MFMA, fused): g = relu(x@W_in^T+b_in)@Wh^T + b_ctx ---
// R19-verified compute. g stored f16 [t][chain][64] (slots 50-63 zeroed) so
// k2's per-step loads are one contiguous 2KB block.
__global__ __launch_bounds__(256, 2) void k1_mfma(
    const float* __restrict__ x, const float* __restrict__ W_in,
    const float* __restrict__ WHT, const float* __restrict__ b_in,
    const float* __restrict__ b_ctx, _Float16* __restrict__ gh) {
  const int lane = threadIdx.x & 63;
  const int wave = threadIdx.x >> 6;
  const int lrow = lane & 15, lgrp = lane >> 4;

#define WA1D(m, kk)                                                     \
  half4 wa1_##m##_##kk;                                                 \
  {                                                                     \
    const int hh = 16 * (m) + lrow;                                     \
    const int j0 = 16 * (kk) + 4 * lgrp;                                \
    const bool v = (hh < HH);                                           \
    const float* p = W_in + (size_t)(v ? hh : 0) * DD + j0;             \
    wa1_##m##_##kk[0] = (_Float16)(v ? p[0] : 0.f);                     \
    wa1_##m##_##kk[1] = (_Float16)(v ? p[1] : 0.f);                     \
    wa1_##m##_##kk[2] = (_Float16)(v ? p[2] : 0.f);                     \
    wa1_##m##_##kk[3] = (_Float16)(v ? p[3] : 0.f);                     \
  }
  WA1D(0, 0) WA1D(0, 1) WA1D(0, 2) WA1D(0, 3)
  WA1D(0, 4) WA1D(0, 5) WA1D(0, 6) WA1D(0, 7)
  WA1D(1, 0) WA1D(1, 1) WA1D(1, 2) WA1D(1, 3)
  WA1D(1, 4) WA1D(1, 5) WA1D(1, 6) WA1D(1, 7)
  WA1D(2, 0) WA1D(2, 1) WA1D(2, 2) WA1D(2, 3)
  WA1D(2, 4) WA1D(2, 5) WA1D(2, 6) WA1D(2, 7)
  WA1D(3, 0) WA1D(3, 1) WA1D(3, 2) WA1D(3, 3)
  WA1D(3, 4) WA1D(3, 5) WA1D(3, 6) WA1D(3, 7)

#define WA2D(m, kk)                                                     \
  half4 wa2_##m##_##kk;                                                 \
  {                                                                     \
    const int gg = 16 * (m) + lrow;                                     \
    const int h0 = 16 * (kk) + 4 * lgrp;                                \
    wa2_##m##_##kk[0] = (_Float16)((gg < HH && h0 + 0 < HH) ? WHT[(h0 + 0) * 52 + gg] : 0.f); \
    wa2_##m##_##kk[1] = (_Float16)((gg < HH && h0 + 1 < HH) ? WHT[(h0 + 1) * 52 + gg] : 0.f); \
    wa2_##m##_##kk[2] = (_Float16)((gg < HH && h0 + 2 < HH) ? WHT[(h0 + 2) * 52 + gg] : 0.f); \
    wa2_##m##_##kk[3] = (_Float16)((gg < HH && h0 + 3 < HH) ? WHT[(h0 + 3) * 52 + gg] : 0.f); \
  }
  WA2D(0, 0) WA2D(0, 1) WA2D(0, 2) WA2D(0, 3)
  WA2D(1, 0) WA2D(1, 1) WA2D(1, 2) WA2D(1, 3)
  WA2D(2, 0) WA2D(2, 1) WA2D(2, 2) WA2D(2, 3)
  WA2D(3, 0) WA2D(3, 1) WA2D(3, 2) WA2D(3, 3)

#define BDEF(m, r)                                                      \
  const float bin_##m##_##r =                                           \
      (16 * (m) + 4 * lgrp + (r) < HH) ? b_in[16 * (m) + 4 * lgrp + (r)] : 0.f; \
  const float bct_##m##_##r =                                           \
      (16 * (m) + 4 * lgrp + (r) < HH) ? b_ctx[16 * (m) + 4 * lgrp + (r)] : 0.f;
  BDEF(0, 0) BDEF(0, 1) BDEF(0, 2) BDEF(0, 3)
  BDEF(1, 0) BDEF(1, 1) BDEF(1, 2) BDEF(1, 3)
  BDEF(2, 0) BDEF(2, 1) BDEF(2, 2) BDEF(2, 3)
  BDEF(3, 0) BDEF(3, 1) BDEF(3, 2) BDEF(3, 3)

  const f32x4 zf = {0.f, 0.f, 0.f, 0.f};

#pragma unroll 1
  for (int it = 0; it < 4; ++it) {
    const int tile = (blockIdx.x * 4 + wave) * 4 + it;
    const int row = tile * 16 + lrow;
    const float* __restrict__ xr = x + (size_t)row * DD + 4 * lgrp;

#define XLD(kk)                                                         \
  half4 xb##kk;                                                         \
  {                                                                     \
    const float4 xv = *reinterpret_cast<const float4*>(xr + 16 * kk);   \
    xb##kk[0] = (_Float16)xv.x;                                         \
    xb##kk[1] = (_Float16)xv.y;                                         \
    xb##kk[2] = (_Float16)xv.z;                                         \
    xb##kk[3] = (_Float16)xv.w;                                         \
  }
    XLD(0) XLD(1) XLD(2) XLD(3) XLD(4) XLD(5) XLD(6) XLD(7)

    f32x4 d10 = zf, d11 = zf, d12 = zf, d13 = zf;
#define MM1(kk)                                                              \
  d10 = __builtin_amdgcn_mfma_f32_16x16x16f16(wa1_0_##kk, xb##kk, d10, 0, 0, 0); \
  d11 = __builtin_amdgcn_mfma_f32_16x16x16f16(wa1_1_##kk, xb##kk, d11, 0, 0, 0); \
  d12 = __builtin_amdgcn_mfma_f32_16x16x16f16(wa1_2_##kk, xb##kk, d12, 0, 0, 0); \
  d13 = __builtin_amdgcn_mfma_f32_16x16x16f16(wa1_3_##kk, xb##kk, d13, 0, 0, 0);
    MM1(0) MM1(1) MM1(2) MM1(3) MM1(4) MM1(5) MM1(6) MM1(7)

#define HBD(k)                                                    \
  half4 hb##k;                                                    \
  hb##k[0] = (_Float16)fmaxf(d1##k[0] + bin_##k##_0, 0.f);        \
  hb##k[1] = (_Float16)fmaxf(d1##k[1] + bin_##k##_1, 0.f);        \
  hb##k[2] = (_Float16)fmaxf(d1##k[2] + bin_##k##_2, 0.f);        \
  hb##k[3] = (_Float16)fmaxf(d1##k[3] + bin_##k##_3, 0.f);
    HBD(0) HBD(1) HBD(2) HBD(3)

    f32x4 d20 = zf, d21 = zf, d22 = zf, d23 = zf;
#define MM2(kk)                                                              \
  d20 = __builtin_amdgcn_mfma_f32_16x16x16f16(wa2_0_##kk, hb##kk, d20, 0, 0, 0); \
  d21 = __builtin_amdgcn_mfma_f32_16x16x16f16(wa2_1_##kk, hb##kk, d21, 0, 0, 0); \
  d22 = __builtin_amdgcn_mfma_f32_16x16x16f16(wa2_2_##kk, hb##kk, d22, 0, 0, 0); \
  d23 = __builtin_amdgcn_mfma_f32_16x16x16f16(wa2_3_##kk, hb##kk, d23, 0, 0, 0);
    MM2(0) MM2(1) MM2(2) MM2(3)

    // store g^T f16 -> gh[((row>>9)*BB + b)*64 + gg]  ([t][chain] layout)
    _Float16* __restrict__ gr =
        gh + ((size_t)(row >> 9) * BB + (row & (BB - 1))) * 64;
#define GST4(off, D, B0, B1, B2, B3)                          \
  {                                                           \
    half4 v;                                                  \
    v[0] = (_Float16)(D[0] + B0);                             \
    v[1] = (_Float16)(D[1] + B1);                             \
    v[2] = (_Float16)(D[2] + B2);                             \
    v[3] = (_Float16)(D[3] + B3);                             \
    *reinterpret_cast<half4*>(gr + (off) + 4 * lgrp) = v;     \
  }
    GST4(0, d20, bct_0_0, bct_0_1, bct_0_2, bct_0_3)
    GST4(16, d21, bct_1_0, bct_1_1, bct_1_2, bct_1_3)
    GST4(32, d22, bct_2_0, bct_2_1, bct_2_2, bct_2_3)
    {
      half4 v;
      v[0] = (_Float16)((lgrp == 0) ? d23[0] + bct_3_0 : 0.f);
      v[1] = (_Float16)((lgrp == 0) ? d23[1] + bct_3_1 : 0.f);
      v[2] = (_Float16)0.f;
      v[3] = (_Float16)0.f;
      *reinterpret_cast<half4*>(gr + 48 + 4 * lgrp) = v;
    }
  }
}

// ---------------- K2: MFMA recurrence (32 blocks x 1 wave) -----------------
// R20 + critical-path fix: the step's 16 MFMAs are now INDEPENDENT (C=0)
// with the K-sum done by a 2-level f32x4 VALU tree — removes the 4-deep
// dependent MFMA chain (MfmaUtil 0.59% said the pipes idled on it).
// g reads come from [t][chain][64] (contiguous 2KB/step). Egress coalesced
// [t][chain][*] (R20-verified).
__global__ __launch_bounds__(64, 1) void k2_mfma(
    const _Float16* __restrict__ gh, const float* __restrict__ WK2T,
    const float* __restrict__ bias2, const float* __restrict__ fc,
    float* __restrict__ ctxT, float* __restrict__ kqT) {
  const int lane = threadIdx.x;
  const int lrow = lane & 15, lgrp = lane >> 4;
  const int chain0 = blockIdx.x * 16;
  const int chain = chain0 + lrow;

#define DECLWF(m, kk)                                                       \
  half4 wf_##m##_##kk;                                                      \
  {                                                                         \
    const int j0 = (kk) * 16 + 4 * lgrp;                                    \
    wf_##m##_##kk[0] = (_Float16)((j0 + 0 < HH) ? WK2T[(j0 + 0) * 64 + (m) * 16 + lrow] : 0.f); \
    wf_##m##_##kk[1] = (_Float16)((j0 + 1 < HH) ? WK2T[(j0 + 1) * 64 + (m) * 16 + lrow] : 0.f); \
    wf_##m##_##kk[2] = (_Float16)((j0 + 2 < HH) ? WK2T[(j0 + 2) * 64 + (m) * 16 + lrow] : 0.f); \
    wf_##m##_##kk[3] = (_Float16)((j0 + 3 < HH) ? WK2T[(j0 + 3) * 64 + (m) * 16 + lrow] : 0.f); \
  }
  DECLWF(0, 0) DECLWF(0, 1) DECLWF(0, 2) DECLWF(0, 3)
  DECLWF(1, 0) DECLWF(1, 1) DECLWF(1, 2) DECLWF(1, 3)
  DECLWF(2, 0) DECLWF(2, 1) DECLWF(2, 2) DECLWF(2, 3)
  DECLWF(3, 0) DECLWF(3, 1) DECLWF(3, 2) DECLWF(3, 3)

  const float bias_0 = bias2[48 + 4 * lgrp + 0];
  const float bias_1 = bias2[48 + 4 * lgrp + 1];
  const float bias_2 = bias2[48 + 4 * lgrp + 2];
  const float bias_3 = bias2[48 + 4 * lgrp + 3];
#define KQR(r)                                            \
  const int row_##r = 48 + 4 * lgrp + r;                  \
  const bool kv_##r = (row_##r >= 50 && row_##r < 60);
  KQR(0) KQR(1) KQR(2) KQR(3)

#define DECLBF(kk)                                                  \
  half4 bf_##kk;                                                    \
  {                                                                 \
    const int j0 = (kk) * 16 + 4 * lgrp;                            \
    bf_##kk[0] = (_Float16)((j0 + 0 < HH) ? fc[j0 + 0] : 0.f);      \
    bf_##kk[1] = (_Float16)((j0 + 1 < HH) ? fc[j0 + 1] : 0.f);      \
    bf_##kk[2] = (_Float16)((j0 + 2 < HH) ? fc[j0 + 2] : 0.f);      \
    bf_##kk[3] = (_Float16)((j0 + 3 < HH) ? fc[j0 + 3] : 0.f);      \
  }
  DECLBF(0) DECLBF(1) DECLBF(2) DECLBF(3)

  // ctx[t=0][chain][h] = c0
  for (int i = lane; i < 16 * 64; i += 64) {
    const int c = i >> 6, h = i & 63;
    ctxT[((size_t)0 * BB + chain0 + c) * 64 + h] = (h < HH) ? fc[h] : 0.f;
  }

  const int gofs = chain * 64 + 4 * lgrp;  // within a [t] slab

  half4 gA0 = *(const half4*)(gh + (size_t)0 * BB * 64 + gofs + 0);
  half4 gA1 = *(const half4*)(gh + (size_t)0 * BB * 64 + gofs + 16);
  half4 gA2 = *(const half4*)(gh + (size_t)0 * BB * 64 + gofs + 32);
  half4 gA3 = *(const half4*)(gh + (size_t)0 * BB * 64 + gofs + 48);
  half4 gB0 = *(const half4*)(gh + (size_t)1 * BB * 64 + gofs + 0);
  half4 gB1 = *(const half4*)(gh + (size_t)1 * BB * 64 + gofs + 16);
  half4 gB2 = *(const half4*)(gh + (size_t)1 * BB * 64 + gofs + 32);
  half4 gB3 = *(const half4*)(gh + (size_t)1 * BB * 64 + gofs + 48);

  const f32x4 zf = {0.f, 0.f, 0.f, 0.f};

#define MMI(E, A, B) \
  const f32x4 E = __builtin_amdgcn_mfma_f32_16x16x16f16(A, B, zf, 0, 0, 0);
#define MSTEP(T, G0, G1, G2, G3, TPF)                                      \
  {                                                                        \
    /* 16 INDEPENDENT MFMAs (no accumulate chain) */                       \
    MMI(e00, wf_0_0, bf_0) MMI(e10, wf_1_0, bf_0)                          \
    MMI(e20, wf_2_0, bf_0) MMI(e30, wf_3_0, bf_0)                          \
    MMI(e01, wf_0_1, bf_1) MMI(e11, wf_1_1, bf_1)                          \
    MMI(e21, wf_2_1, bf_1) MMI(e31, wf_3_1, bf_1)                          \
    MMI(e02, wf_0_2, bf_2) MMI(e12, wf_1_2, bf_2)                          \
    MMI(e22, wf_2_2, bf_2) MMI(e32, wf_3_2, bf_2)                          \
    MMI(e03, wf_0_3, bf_3) MMI(e13, wf_1_3, bf_3)                          \
    MMI(e23, wf_2_3, bf_3) MMI(e33, wf_3_3, bf_3)                          \
    const f32x4 d0 = (e00 + e01) + (e02 + e03);                            \
    const f32x4 d1 = (e10 + e11) + (e12 + e13);                            \
    const f32x4 d2 = (e20 + e21) + (e22 + e23);                            \
    const f32x4 d3 = (e30 + e31) + (e32 + e33);                            \
    {                                                                      \
      float* kqo = kqT + ((size_t)(T) * BB + chain) * 12;                  \
      if (kv_0) kqo[row_0 - 50] = d3[0] + bias_0;                          \
      if (kv_1) kqo[row_1 - 50] = d3[1] + bias_1;                          \
      if (kv_2) kqo[row_2 - 50] = d3[2] + bias_2;                          \
      if (kv_3) kqo[row_3 - 50] = d3[3] + bias_3;                          \
    }                                                                      \
    const float cn_0_0 = fmaxf(d0[0] + (float)G0[0], 0.f);                 \
    const float cn_0_1 = fmaxf(d0[1] + (float)G0[1], 0.f);                 \
    const float cn_0_2 = fmaxf(d0[2] + (float)G0[2], 0.f);                 \
    const float cn_0_3 = fmaxf(d0[3] + (float)G0[3], 0.f);                 \
    const float cn_1_0 = fmaxf(d1[0] + (float)G1[0], 0.f);                 \
    const float cn_1_1 = fmaxf(d1[1] + (float)G1[1], 0.f);                 \
    const float cn_1_2 = fmaxf(d1[2] + (float)G1[2], 0.f);                 \
    const float cn_1_3 = fmaxf(d1[3] + (float)G1[3], 0.f);                 \
    const float cn_2_0 = fmaxf(d2[0] + (float)G2[0], 0.f);                 \
    const float cn_2_1 = fmaxf(d2[1] + (float)G2[1], 0.f);                 \
    const float cn_2_2 = fmaxf(d2[2] + (float)G2[2], 0.f);                 \
    const float cn_2_3 = fmaxf(d2[3] + (float)G2[3], 0.f);                 \
    const float cn_3_0 = fmaxf(d3[0] + (float)G3[0], 0.f);                 \
    const float cn_3_1 = fmaxf(d3[1] + (float)G3[1], 0.f);                 \
    const float cn_3_2 = fmaxf(d3[2] + (float)G3[2], 0.f);                 \
    const float cn_3_3 = fmaxf(d3[3] + (float)G3[3], 0.f);                 \
    {                                                                      \
      const size_t tp = (size_t)((TPF) < TT ? (TPF) : TT - 1) * BB * 64;   \
      G0 = *(const half4*)(gh + tp + gofs + 0);                            \
      G1 = *(const half4*)(gh + tp + gofs + 16);                           \
      G2 = *(const half4*)(gh + tp + gofs + 32);                           \
      G3 = *(const half4*)(gh + tp + gofs + 48);                           \
    }                                                                      \
    float* cto = ctxT + ((size_t)((T) + 1) * BB + chain) * 64 + 4 * lgrp;  \
    *reinterpret_cast<float4*>(cto + 0) =                                  \
        make_float4(cn_0_0, cn_0_1, cn_0_2, cn_0_3);                       \
    *reinterpret_cast<float4*>(cto + 16) =                                 \
        make_float4(cn_1_0, cn_1_1, cn_1_2, cn_1_3);                       \
    *reinterpret_cast<float4*>(cto + 32) =                                 \
        make_float4(cn_2_0, cn_2_1, cn_2_2, cn_2_3);                       \
    *reinterpret_cast<float4*>(cto + 48) =                                 \
        make_float4(cn_3_0, cn_3_1, cn_3_2, cn_3_3);                       \
    bf_0[0] = (_Float16)cn_0_0; bf_0[1] = (_Float16)cn_0_1;                \
    bf_0[2] = (_Float16)cn_0_2; bf_0[3] = (_Float16)cn_0_3;                \
    bf_1[0] = (_Float16)cn_1_0; bf_1[1] = (_Float16)cn_1_1;                \
    bf_1[2] = (_Float16)cn_1_2; bf_1[3] = (_Float16)cn_1_3;                \
    bf_2[0] = (_Float16)cn_2_0; bf_2[1] = (_Float16)cn_2_1;                \
    bf_2[2] = (_Float16)cn_2_2; bf_2[3] = (_Float16)cn_2_3;                \
    bf_3[0] = (_Float16)cn_3_0; bf_3[1] = (_Float16)cn_3_1;                \
    bf_3[2] = (_Float16)cn_3_2; bf_3[3] = (_Float16)cn_3_3;                \
  }

#pragma unroll 1
  for (int t = 0; t < TT; t += 2) {
    MSTEP(t, gA0, gA1, gA2, gA3, t + 2)
    MSTEP(t + 1, gB0, gB1, gB2, gB3, t + 3)
  }

  {  // tail: key/q of c_TT at index TT
    MMI(e30, wf_3_0, bf_0) MMI(e31, wf_3_1, bf_1)
    MMI(e32, wf_3_2, bf_2) MMI(e33, wf_3_3, bf_3)
    const f32x4 d3 = (e30 + e31) + (e32 + e33);
    float* kqo = kqT + ((size_t)TT * BB + chain) * 12;
    if (kv_0) kqo[row_0 - 50] = d3[0] + bias_0;
    if (kv_1) kqo[row_1 - 50] = d3[1] + bias_1;
    if (kv_2) kqo[row_2 - 50] = d3[2] + bias_2;
    if (kv_3) kqo[row_3 - 50] = d3[3] + bias_3;
  }
}

// ---------------- K3: MFMA flash attention (R20-verified, unchanged) -------
__global__ __launch_bounds__(256, 4) void k3_attn(
    const float* __restrict__ ctxT, const float* __restrict__ kqT,
    const float* __restrict__ W_act, const float* __restrict__ b_act,
    float* __restrict__ out) {
  __shared__ __align__(16) float ct[64 * 66];
  __shared__ __align__(16) float k_l[16 * 68];
  __shared__ __align__(16) float o_l[64 * 66];
  __shared__ float su_l[64];

  const int tid = threadIdx.x;
  const int bid = blockIdx.x;
  const int chunk = 3 - (bid >> 9);  // heavy-first
  const int b = bid & 511;
  const int tbase = chunk * 64;
  const int nst = min(tbase + 66, 257);
  const int ntiles = (nst + 63) >> 6;
  const int wave = tid >> 6;
  const int lane = tid & 63;
  const int lrow = lane & 15;
  const int lgrp = lane >> 4;
  const int tw = tbase + wave * 16;

  for (int i = tid; i < 11 * 68; i += 256) k_l[5 * 68 + i] = 0.f;

  half4 qf;
#pragma unroll
  for (int i = 0; i < 4; ++i) {
    const int k = 4 * lgrp + i;
    qf[i] = (_Float16)(
        (k < KK) ? kqT[((size_t)(tw + lrow + 1) * BB + b) * 12 + 5 + k] : 0.f);
  }

  const f32x4 zf = {0.f, 0.f, 0.f, 0.f};
  f32x4 acc0 = zf, acc1 = zf, acc2 = zf, acc3 = zf;
  float su = 0.f;

#pragma unroll 1
  for (int tile = 0; tile < ntiles; ++tile) {
    __syncthreads();
    {
      const int r = tid >> 2;
      const int c0 = (tid & 3) * 16;
      const int srow = tile * 64 + r;
      const float* src = ctxT + ((size_t)srow * BB + b) * 64;
      const bool sv = (srow < nst);
#pragma unroll
      for (int u = 0; u < 8; ++u) {
        const int c = c0 + u * 2;
        float2 v = make_float2(0.f, 0.f);
        if (sv && c < HH) v = *reinterpret_cast<const float2*>(src + c);
        *reinterpret_cast<float2*>(&ct[r * 66 + c]) = v;
      }
    }
    {
      for (int i = tid; i < KK * 64; i += 256) {
        const int k = i >> 6, sl = i & 63;
        const int s = tile * 64 + sl;
        k_l[k * 68 + sl] =
            (s <= TT) ? kqT[((size_t)s * BB + b) * 12 + k] : 0.f;
      }
    }
    __syncthreads();

    if (tile * 64 <= tw + 16) {
#pragma unroll 1
      for (int su16 = 0; su16 < 4; ++su16) {
        const int sb = tile * 64 + su16 * 16;
        if (sb > tw + 16) break;

        half4 kf;
#pragma unroll
        for (int i = 0; i < 4; ++i)
          kf[i] = (_Float16)k_l[(4 * lgrp + i) * 68 + su16 * 16 + lrow];

        const f32x4 sc =
            __builtin_amdgcn_mfma_f32_16x16x16f16(kf, qf, zf, 0, 0, 0);

        half4 pa;
#pragma unroll
        for (int r = 0; r < 4; ++r) {
          const int s = sb + 4 * lgrp + r;
          const float p = (s <= tw + lrow + 1) ? __expf(sc[r]) : 0.f;
          su += p;
          pa[r] = (_Float16)p;
        }

        const int vbase = su16 * 16 + 4 * lgrp;
#define PVHT(HT, ACC)                                                     \
  {                                                                       \
    half4 vf;                                                             \
    vf[0] = (_Float16)ct[(vbase + 0) * 66 + lrow + 16 * HT];              \
    vf[1] = (_Float16)ct[(vbase + 1) * 66 + lrow + 16 * HT];              \
    vf[2] = (_Float16)ct[(vbase + 2) * 66 + lrow + 16 * HT];              \
    vf[3] = (_Float16)ct[(vbase + 3) * 66 + lrow + 16 * HT];              \
    ACC = __builtin_amdgcn_mfma_f32_16x16x16f16(pa, vf, ACC, 0, 0, 0);    \
  }
        PVHT(0, acc0) PVHT(1, acc1) PVHT(2, acc2) PVHT(3, acc3)
      }
    }
  }

  su += __shfl_xor(su, 16, 64);
  su += __shfl_xor(su, 32, 64);
  if (lane < 16) su_l[wave * 16 + lane] = su;

#pragma unroll
  for (int r = 0; r < 4; ++r) {
    const int trow = wave * 16 + 4 * lgrp + r;
    o_l[trow * 66 + lrow + 0] = acc0[r];
    o_l[trow * 66 + lrow + 16] = acc1[r];
    o_l[trow * 66 + lrow + 32] = acc2[r];
    o_l[trow * 66 + lrow + 48] = acc3[r];
  }
  __syncthreads();

  {
    const int tl = tid >> 2;
    const int a = tid & 3;
    const float inv = 1.f / su_l[tl];
    const float* orow = &o_l[tl * 66];
    const float* wrow = W_act + a * HH;
    float s0 = 0.f, s1 = 0.f;
#pragma unroll
    for (int h = 0; h < HH; h += 2) {
      s0 = fmaf(orow[h], wrow[h], s0);
      s1 = fmaf(orow[h + 1], wrow[h + 1], s1);
    }
    out[((size_t)(tbase + tl) * BB + b) * AA + a] =
        fmaf(s0 + s1, inv, b_act[a]);
  }
}

extern "C" void kernel_launch(void* const* d_in, const int* in_sizes, int n_in,
                              void* d_out, int out_size, void* d_ws,
                              size_t ws_size, hipStream_t stream) {
  const float* x = (const float*)d_in[0];
  const float* W_in = (const float*)d_in[1];
  const float* b_in = (const float*)d_in[2];
  const float* W_ctx = (const float*)d_in[3];
  const float* b_ctx = (const float*)d_in[4];
  const float* W_key = (const float*)d_in[5];
  const float* b_key = (const float*)d_in[6];
  const float* W_q = (const float*)d_in[7];
  const float* b_q = (const float*)d_in[8];
  const float* fc = (const float*)d_in[9];
  const float* W_act = (const float*)d_in[10];
  const float* b_act = (const float*)d_in[11];
  float* out = (float*)d_out;
  float* ws = (float*)d_ws;

  float* WHT = ws;                                  // 50*52
  float* WK2T = ws + 4096;                          // 50*64
  float* bias2 = ws + 8128;                         // 64
  _Float16* gh = (_Float16*)(ws + 8192);            // [t][chain][64] f16
  float* ctxT = ws + 8192 + 4194304;                // [t][chain][64] f32
  float* kqT = ctxT + (size_t)257 * BB * 64;        // [t][chain][12] f32
  // total ~57 MB

  hipLaunchKernelGGL(k0_prep, dim3(26), dim3(256), 0, stream, W_in, W_ctx,
                     W_key, W_q, b_key, b_q, WHT, WK2T, bias2);
  hipLaunchKernelGGL(k1_mfma, dim3(512), dim3(256), 0, stream, x, W_in, WHT,
                     b_in, b_ctx, gh);
  hipLaunchKernelGGL(k2_mfma, dim3(32), dim3(64), 0, stream, gh, WK2T, bias2,
                     fc, ctxT, kqT);
  hipLaunchKernelGGL(k3_attn, dim3(2048), dim3(256), 0, stream, ctxT, kqT,
                     W_act, b_act, out);
}

// Round 22
// 151.102 us; speedup vs baseline: 1.4980x; 1.4980x over previous
//
#include <hip/hip_runtime.h>

#define TT 256
#define BB 512
#define DD 128
#define HH 50
#define KK 5
#define AA 4
#define NROW 131072
#define GST 52           // g row stride (16B-aligned float4 slots)
#define KQS 260          // kqg row stride

#define R50(X) X(0) X(1) X(2) X(3) X(4) X(5) X(6) X(7) X(8) X(9) \
  X(10) X(11) X(12) X(13) X(14) X(15) X(16) X(17) X(18) X(19) \
  X(20) X(21) X(22) X(23) X(24) X(25) X(26) X(27) X(28) X(29) \
  X(30) X(31) X(32) X(33) X(34) X(35) X(36) X(37) X(38) X(39) \
  X(40) X(41) X(42) X(43) X(44) X(45) X(46) X(47) X(48) X(49)

typedef _Float16 half4 __attribute__((ext_vector_type(4)));
typedef float f32x4 __attribute__((ext_vector_type(4)));

// ---------------- K0: weight prep ----------------
__global__ void k0_prep(const float* __restrict__ W_in,
                        const float* __restrict__ W_ctx,
                        const float* __restrict__ W_key,
                        const float* __restrict__ W_q,
                        const float* __restrict__ b_key,
                        const float* __restrict__ b_q,
                        float* __restrict__ WHT,
                        float* __restrict__ WK2T, float* __restrict__ bias2) {
  int i = blockIdx.x * 256 + threadIdx.x;
  if (i < HH * 52) {
    int j = i / 52, h = i % 52;
    WHT[i] = (h < HH) ? W_ctx[h * (2 * HH) + HH + j] : 0.f;
  }
  if (i < HH * 64) {
    int j = i >> 6, l = i & 63;
    float v = 0.f;
    if (l < HH) v = W_ctx[l * (2 * HH) + j];
    else if (l < HH + KK) v = W_key[(l - HH) * HH + j];
    else if (l < HH + 2 * KK) v = W_q[(l - HH - KK) * HH + j];
    WK2T[i] = v;
  }
  if (i < 64) {
    float bv = 0.f;
    if (i >= HH && i < HH + KK) bv = b_key[i - HH];
    else if (i >= HH + KK && i < HH + 2 * KK) bv = b_q[i - HH - KK];
    bias2[i] = bv;
  }
}

// ---------------- K1 (MFMA, fused): g = relu(x@W_in^T+b_in)@Wh^T + b_ctx ---
// Per 16-row tile: pass1 h^T = W_in(A) x^T(B), K=128 (32 MFMA); bias+relu
// in-lane; D-frag==B-frag identity feeds pass2 g^T = Wh(A) h^T(B), K=64
// zero-padded (16 MFMA). No LDS, no barriers, no intermediate buffer.
// g stored in k2's chain layout g[(b*TT+t)*GST + gg].
__global__ __launch_bounds__(256, 2) void k1_mfma(
    const float* __restrict__ x, const float* __restrict__ W_in,
    const float* __restrict__ WHT, const float* __restrict__ b_in,
    const float* __restrict__ b_ctx, float* __restrict__ g) {
  const int lane = threadIdx.x & 63;
  const int wave = threadIdx.x >> 6;
  const int lrow = lane & 15, lgrp = lane >> 4;

#define WA1D(m, kk)                                                     \
  half4 wa1_##m##_##kk;                                                 \
  {                                                                     \
    const int hh = 16 * (m) + lrow;                                     \
    const int j0 = 16 * (kk) + 4 * lgrp;                                \
    const bool v = (hh < HH);                                           \
    const float* p = W_in + (size_t)(v ? hh : 0) * DD + j0;             \
    wa1_##m##_##kk[0] = (_Float16)(v ? p[0] : 0.f);                     \
    wa1_##m##_##kk[1] = (_Float16)(v ? p[1] : 0.f);                     \
    wa1_##m##_##kk[2] = (_Float16)(v ? p[2] : 0.f);                     \
    wa1_##m##_##kk[3] = (_Float16)(v ? p[3] : 0.f);                     \
  }
  WA1D(0, 0) WA1D(0, 1) WA1D(0, 2) WA1D(0, 3)
  WA1D(0, 4) WA1D(0, 5) WA1D(0, 6) WA1D(0, 7)
  WA1D(1, 0) WA1D(1, 1) WA1D(1, 2) WA1D(1, 3)
  WA1D(1, 4) WA1D(1, 5) WA1D(1, 6) WA1D(1, 7)
  WA1D(2, 0) WA1D(2, 1) WA1D(2, 2) WA1D(2, 3)
  WA1D(2, 4) WA1D(2, 5) WA1D(2, 6) WA1D(2, 7)
  WA1D(3, 0) WA1D(3, 1) WA1D(3, 2) WA1D(3, 3)
  WA1D(3, 4) WA1D(3, 5) WA1D(3, 6) WA1D(3, 7)

#define WA2D(m, kk)                                                     \
  half4 wa2_##m##_##kk;                                                 \
  {                                                                     \
    const int gg = 16 * (m) + lrow;                                     \
    const int h0 = 16 * (kk) + 4 * lgrp;                                \
    wa2_##m##_##kk[0] = (_Float16)((gg < HH && h0 + 0 < HH) ? WHT[(h0 + 0) * 52 + gg] : 0.f); \
    wa2_##m##_##kk[1] = (_Float16)((gg < HH && h0 + 1 < HH) ? WHT[(h0 + 1) * 52 + gg] : 0.f); \
    wa2_##m##_##kk[2] = (_Float16)((gg < HH && h0 + 2 < HH) ? WHT[(h0 + 2) * 52 + gg] : 0.f); \
    wa2_##m##_##kk[3] = (_Float16)((gg < HH && h0 + 3 < HH) ? WHT[(h0 + 3) * 52 + gg] : 0.f); \
  }
  WA2D(0, 0) WA2D(0, 1) WA2D(0, 2) WA2D(0, 3)
  WA2D(1, 0) WA2D(1, 1) WA2D(1, 2) WA2D(1, 3)
  WA2D(2, 0) WA2D(2, 1) WA2D(2, 2) WA2D(2, 3)
  WA2D(3, 0) WA2D(3, 1) WA2D(3, 2) WA2D(3, 3)

#define BDEF(m, r)                                                      \
  const float bin_##m##_##r =                                           \
      (16 * (m) + 4 * lgrp + (r) < HH) ? b_in[16 * (m) + 4 * lgrp + (r)] : 0.f; \
  const float bct_##m##_##r =                                           \
      (16 * (m) + 4 * lgrp + (r) < HH) ? b_ctx[16 * (m) + 4 * lgrp + (r)] : 0.f;
  BDEF(0, 0) BDEF(0, 1) BDEF(0, 2) BDEF(0, 3)
  BDEF(1, 0) BDEF(1, 1) BDEF(1, 2) BDEF(1, 3)
  BDEF(2, 0) BDEF(2, 1) BDEF(2, 2) BDEF(2, 3)
  BDEF(3, 0) BDEF(3, 1) BDEF(3, 2) BDEF(3, 3)

  const f32x4 zf = {0.f, 0.f, 0.f, 0.f};

#pragma unroll 1
  for (int it = 0; it < 4; ++it) {
    const int tile = (blockIdx.x * 4 + wave) * 4 + it;
    const int row = tile * 16 + lrow;
    const float* __restrict__ xr = x + (size_t)row * DD + 4 * lgrp;

#define XLD(kk)                                                         \
  half4 xb##kk;                                                         \
  {                                                                     \
    const float4 xv = *reinterpret_cast<const float4*>(xr + 16 * kk);   \
    xb##kk[0] = (_Float16)xv.x;                                         \
    xb##kk[1] = (_Float16)xv.y;                                         \
    xb##kk[2] = (_Float16)xv.z;                                         \
    xb##kk[3] = (_Float16)xv.w;                                         \
  }
    XLD(0) XLD(1) XLD(2) XLD(3) XLD(4) XLD(5) XLD(6) XLD(7)

    f32x4 d10 = zf, d11 = zf, d12 = zf, d13 = zf;
#define MM1(kk)                                                              \
  d10 = __builtin_amdgcn_mfma_f32_16x16x16f16(wa1_0_##kk, xb##kk, d10, 0, 0, 0); \
  d11 = __builtin_amdgcn_mfma_f32_16x16x16f16(wa1_1_##kk, xb##kk, d11, 0, 0, 0); \
  d12 = __builtin_amdgcn_mfma_f32_16x16x16f16(wa1_2_##kk, xb##kk, d12, 0, 0, 0); \
  d13 = __builtin_amdgcn_mfma_f32_16x16x16f16(wa1_3_##kk, xb##kk, d13, 0, 0, 0);
    MM1(0) MM1(1) MM1(2) MM1(3) MM1(4) MM1(5) MM1(6) MM1(7)

#define HBD(k)                                                    \
  half4 hb##k;                                                    \
  hb##k[0] = (_Float16)fmaxf(d1##k[0] + bin_##k##_0, 0.f);        \
  hb##k[1] = (_Float16)fmaxf(d1##k[1] + bin_##k##_1, 0.f);        \
  hb##k[2] = (_Float16)fmaxf(d1##k[2] + bin_##k##_2, 0.f);        \
  hb##k[3] = (_Float16)fmaxf(d1##k[3] + bin_##k##_3, 0.f);
    HBD(0) HBD(1) HBD(2) HBD(3)

    f32x4 d20 = zf, d21 = zf, d22 = zf, d23 = zf;
#define MM2(kk)                                                              \
  d20 = __builtin_amdgcn_mfma_f32_16x16x16f16(wa2_0_##kk, hb##kk, d20, 0, 0, 0); \
  d21 = __builtin_amdgcn_mfma_f32_16x16x16f16(wa2_1_##kk, hb##kk, d21, 0, 0, 0); \
  d22 = __builtin_amdgcn_mfma_f32_16x16x16f16(wa2_2_##kk, hb##kk, d22, 0, 0, 0); \
  d23 = __builtin_amdgcn_mfma_f32_16x16x16f16(wa2_3_##kk, hb##kk, d23, 0, 0, 0);
    MM2(0) MM2(1) MM2(2) MM2(3)

    // store g^T[gg][row] -> g[(b*TT + t)*GST + gg]; rows of a tile share t
    float* __restrict__ gr =
        g + ((size_t)(row & (BB - 1)) * TT + (row >> 9)) * GST;
    *reinterpret_cast<float4*>(gr + 4 * lgrp) =
        make_float4(d20[0] + bct_0_0, d20[1] + bct_0_1, d20[2] + bct_0_2,
                    d20[3] + bct_0_3);
    *reinterpret_cast<float4*>(gr + 16 + 4 * lgrp) =
        make_float4(d21[0] + bct_1_0, d21[1] + bct_1_1, d21[2] + bct_1_2,
                    d21[3] + bct_1_3);
    *reinterpret_cast<float4*>(gr + 32 + 4 * lgrp) =
        make_float4(d22[0] + bct_2_0, d22[1] + bct_2_1, d22[2] + bct_2_2,
                    d22[3] + bct_2_3);
    if (lgrp == 0) {  // gg 48,49 valid; 50,51 stored as 0
      *reinterpret_cast<float4*>(gr + 48) =
          make_float4(d23[0] + bct_3_0, d23[1] + bct_3_1, 0.f, 0.f);
    }
  }
}

// ---------------- K2: per-batch recurrence (512 blocks x 1 wave) -----------
// R12 scalar core + register-batched kq egress (R17/R18, measured 80.7us).
// g layout: g[(b*TT + t)*GST + gg], gslot = lane (linear, GST=52).
__global__ __launch_bounds__(64) void k2_rec(
    const float* __restrict__ g, const float* __restrict__ WK2T,
    const float* __restrict__ bias2, const float* __restrict__ first_context,
    float* __restrict__ ctxg, float* __restrict__ kqg) {
  __shared__ __align__(16) float c_lds[64];
  const int b = blockIdx.x;
  const int lane = threadIdx.x;

#define WDECL(j)                            \
  float w##j = WK2T[(j) * 64 + lane];       \
  asm volatile("" : "+v"(w##j));
  R50(WDECL)
  const float wz = 0.f;
  const float bias = bias2[lane];

  const float c0v = (lane < HH) ? first_context[lane] : 0.f;
  c_lds[lane] = (lane < HH) ? c0v : 0.f;
  if (lane < HH) ctxg[((size_t)b * 257 + 0) * HH + lane] = c0v;

  const int gslot = (lane < GST) ? lane : (GST - 1);
  const float* __restrict__ gbp = g + (size_t)b * TT * GST + gslot;
  float gq0 = gbp[0 * GST];
  float gq1 = gbp[1 * GST];
  float gq2 = gbp[2 * GST];
  float gq3 = gbp[3 * GST];

  const bool iskq = (lane >= HH && lane < HH + 2 * KK);
  float* __restrict__ kqrow =
      kqg + ((size_t)b * 10 + (iskq ? lane - HH : 0)) * KQS;

#define KQ(J, wa, wb, wc, wd)                                            \
  {                                                                      \
    const float4 cq = *reinterpret_cast<const float4*>(&c_lds[J]);       \
    acc0 = fmaf(wa, cq.x, acc0);                                         \
    acc1 = fmaf(wb, cq.y, acc1);                                         \
    acc2 = fmaf(wc, cq.z, acc2);                                         \
    acc3 = fmaf(wd, cq.w, acc3);                                         \
  }
#define DOT50R                                                           \
  float acc0 = 0.f, acc1 = 0.f, acc2 = 0.f, acc3 = 0.f;                  \
  KQ(0, w0, w1, w2, w3) KQ(4, w4, w5, w6, w7)                            \
  KQ(8, w8, w9, w10, w11) KQ(12, w12, w13, w14, w15)                     \
  KQ(16, w16, w17, w18, w19) KQ(20, w20, w21, w22, w23)                  \
  KQ(24, w24, w25, w26, w27) KQ(28, w28, w29, w30, w31)                  \
  KQ(32, w32, w33, w34, w35) KQ(36, w36, w37, w38, w39)                  \
  KQ(40, w40, w41, w42, w43) KQ(44, w44, w45, w46, w47)                  \
  KQ(48, w48, w49, wz, wz)                                               \
  const float acc = (acc0 + acc1) + (acc2 + acc3);

#define BODY(RR, GQ)                                                     \
  {                                                                      \
    const int t = tg4 + RR;                                              \
    DOT50R                                                               \
    kqa##RR = acc + bias;                                                \
    const float cn = fmaxf(acc + GQ, 0.f);                               \
    GQ = gbp[(size_t)min(t + 4, TT - 1) * GST];                          \
    if (lane < HH) {                                                     \
      ctxg[((size_t)b * 257 + (t + 1)) * HH + lane] = cn;                \
      c_lds[lane] = cn;                                                  \
    }                                                                    \
  }

#pragma unroll 1
  for (int tg4 = 0; tg4 < TT; tg4 += 4) {
    float kqa0, kqa1, kqa2, kqa3;
    BODY(0, gq0) BODY(1, gq1) BODY(2, gq2) BODY(3, gq3)
    if (iskq) {
      *reinterpret_cast<float4*>(kqrow + tg4) =
          make_float4(kqa0, kqa1, kqa2, kqa3);
    }
  }

  {  // tail: key/q of c_TT at index TT
    DOT50R
    if (iskq) kqrow[TT] = acc + bias;
  }
}

// ---------------- K3: MFMA flash attention, LDS-staged (R17, passing) ------
__global__ __launch_bounds__(256, 4) void k3_attn(
    const float* __restrict__ ctxg, const float* __restrict__ kqg,
    const float* __restrict__ W_act, const float* __restrict__ b_act,
    float* __restrict__ out) {
  __shared__ __align__(16) float ct[64 * 66];
  __shared__ __align__(16) float k_l[16 * 68];  // rows 5-15 hard-zeroed
  __shared__ __align__(16) float o_l[64 * 66];
  __shared__ float su_l[64];

  const int tid = threadIdx.x;
  const int bid = blockIdx.x;
  const int chunk = 3 - (bid >> 9);
  const int b = bid & 511;
  const int tbase = chunk * 64;
  const int nst = min(tbase + 66, 257);
  const int ntiles = (nst + 63) >> 6;
  const int wave = tid >> 6;
  const int lane = tid & 63;
  const int lrow = lane & 15;
  const int lgrp = lane >> 4;
  const int tw = tbase + wave * 16;

  for (int i = tid; i < 11 * 68; i += 256) k_l[5 * 68 + i] = 0.f;

  half4 qf;
#pragma unroll
  for (int i = 0; i < 4; ++i) {
    const int k = 4 * lgrp + i;
    qf[i] = (_Float16)((k < KK)
                           ? kqg[((size_t)b * 10 + 5 + k) * KQS + tw + lrow + 1]
                           : 0.f);
  }

  const f32x4 zf = {0.f, 0.f, 0.f, 0.f};
  f32x4 acc0 = zf, acc1 = zf, acc2 = zf, acc3 = zf;
  float su = 0.f;

#pragma unroll 1
  for (int tile = 0; tile < ntiles; ++tile) {
    __syncthreads();
    {
      const int r = tid >> 2;
      const int c0 = (tid & 3) * 16;
      const int srow = tile * 64 + r;
      const float* src = ctxg + ((size_t)b * 257 + srow) * HH;
      const bool sv = (srow < nst);
#pragma unroll
      for (int u = 0; u < 8; ++u) {
        const int c = c0 + u * 2;
        float2 v = make_float2(0.f, 0.f);
        if (sv && c < HH) v = *reinterpret_cast<const float2*>(src + c);
        *reinterpret_cast<float2*>(&ct[r * 66 + c]) = v;
      }
    }
    {
      for (int i = tid; i < KK * 64; i += 256) {
        const int k = i >> 6, sl = i & 63;
        const int s = tile * 64 + sl;
        k_l[k * 68 + sl] =
            (s <= TT) ? kqg[((size_t)b * 10 + k) * KQS + s] : 0.f;
      }
    }
    __syncthreads();

    if (tile * 64 <= tw + 16) {
#pragma unroll 1
      for (int su16 = 0; su16 < 4; ++su16) {
        const int sb = tile * 64 + su16 * 16;
        if (sb > tw + 16) break;

        half4 kf;
#pragma unroll
        for (int i = 0; i < 4; ++i)
          kf[i] = (_Float16)k_l[(4 * lgrp + i) * 68 + su16 * 16 + lrow];

        const f32x4 sc =
            __builtin_amdgcn_mfma_f32_16x16x16f16(kf, qf, zf, 0, 0, 0);

        half4 pa;
#pragma unroll
        for (int r = 0; r < 4; ++r) {
          const int s = sb + 4 * lgrp + r;
          const float p = (s <= tw + lrow + 1) ? __expf(sc[r]) : 0.f;
          su += p;
          pa[r] = (_Float16)p;
        }

        const int vbase = su16 * 16 + 4 * lgrp;
#define PVHT(HT, ACC)                                                     \
  {                                                                       \
    half4 vf;                                                             \
    vf[0] = (_Float16)ct[(vbase + 0) * 66 + lrow + 16 * HT];              \
    vf[1] = (_Float16)ct[(vbase + 1) * 66 + lrow + 16 * HT];              \
    vf[2] = (_Float16)ct[(vbase + 2) * 66 + lrow + 16 * HT];              \
    vf[3] = (_Float16)ct[(vbase + 3) * 66 + lrow + 16 * HT];              \
    ACC = __builtin_amdgcn_mfma_f32_16x16x16f16(pa, vf, ACC, 0, 0, 0);    \
  }
        PVHT(0, acc0) PVHT(1, acc1) PVHT(2, acc2) PVHT(3, acc3)
      }
    }
  }

  su += __shfl_xor(su, 16, 64);
  su += __shfl_xor(su, 32, 64);
  if (lane < 16) su_l[wave * 16 + lane] = su;

#pragma unroll
  for (int r = 0; r < 4; ++r) {
    const int trow = wave * 16 + 4 * lgrp + r;
    o_l[trow * 66 + lrow + 0] = acc0[r];
    o_l[trow * 66 + lrow + 16] = acc1[r];
    o_l[trow * 66 + lrow + 32] = acc2[r];
    o_l[trow * 66 + lrow + 48] = acc3[r];
  }
  __syncthreads();

  {
    const int tl = tid >> 2;
    const int a = tid & 3;
    const float inv = 1.f / su_l[tl];
    const float* orow = &o_l[tl * 66];
    const float* wrow = W_act + a * HH;
    float s0 = 0.f, s1 = 0.f;
#pragma unroll
    for (int h = 0; h < HH; h += 2) {
      s0 = fmaf(orow[h], wrow[h], s0);
      s1 = fmaf(orow[h + 1], wrow[h + 1], s1);
    }
    out[((size_t)(tbase + tl) * BB + b) * AA + a] =
        fmaf(s0 + s1, inv, b_act[a]);
  }
}

extern "C" void kernel_launch(void* const* d_in, const int* in_sizes, int n_in,
                              void* d_out, int out_size, void* d_ws,
                              size_t ws_size, hipStream_t stream) {
  const float* x = (const float*)d_in[0];
  const float* W_in = (const float*)d_in[1];
  const float* b_in = (const float*)d_in[2];
  const float* W_ctx = (const float*)d_in[3];
  const float* b_ctx = (const float*)d_in[4];
  const float* W_key = (const float*)d_in[5];
  const float* b_key = (const float*)d_in[6];
  const float* W_q = (const float*)d_in[7];
  const float* b_q = (const float*)d_in[8];
  const float* fc = (const float*)d_in[9];
  const float* W_act = (const float*)d_in[10];
  const float* b_act = (const float*)d_in[11];
  float* out = (float*)d_out;
  float* ws = (float*)d_ws;

  float* WHT = ws;                                 // 50*52
  float* WK2T = ws + 4096;                         // 50*64
  float* bias2 = ws + 8128;                        // 64
  float* g = ws + 8192;                            // 131072*52 (+64 pad)
  float* ctxg = g + (size_t)NROW * GST + 64;       // 512*257*50
  float* kqg = ctxg + (size_t)BB * 257 * HH;       // 512*10*260
  // total ~55 MB

  hipLaunchKernelGGL(k0_prep, dim3(26), dim3(256), 0, stream, W_in, W_ctx,
                     W_key, W_q, b_key, b_q, WHT, WK2T, bias2);
  hipLaunchKernelGGL(k1_mfma, dim3(512), dim3(256), 0, stream, x, W_in, WHT,
                     b_in, b_ctx, g);
  hipLaunchKernelGGL(k2_rec, dim3(512), dim3(64), 0, stream, g, WK2T, bias2,
                     fc, ctxg, kqg);
  hipLaunchKernelGGL(k3_attn, dim3(2048), dim3(256), 0, stream, ctxg, kqg,
                     W_act, b_act, out);
}

// Round 23
// 145.040 us; speedup vs baseline: 1.5606x; 1.0418x over previous
//
#include <hip/hip_runtime.h>

#define TT 256
#define BB 512
#define DD 128
#define HH 50
#define KK 5
#define AA 4
#define NROW 131072
#define GST 52           // g row stride (16B-aligned float4 slots)
#define CXS 66           // ctx_l row stride (f16)
#define KQR2 18          // kq_l row stride (f16)

#define R50(X) X(0) X(1) X(2) X(3) X(4) X(5) X(6) X(7) X(8) X(9) \
  X(10) X(11) X(12) X(13) X(14) X(15) X(16) X(17) X(18) X(19) \
  X(20) X(21) X(22) X(23) X(24) X(25) X(26) X(27) X(28) X(29) \
  X(30) X(31) X(32) X(33) X(34) X(35) X(36) X(37) X(38) X(39) \
  X(40) X(41) X(42) X(43) X(44) X(45) X(46) X(47) X(48) X(49)

typedef _Float16 half4 __attribute__((ext_vector_type(4)));
typedef float f32x4 __attribute__((ext_vector_type(4)));

// ---------------- K0: weight prep ----------------
__global__ void k0_prep(const float* __restrict__ W_in,
                        const float* __restrict__ W_ctx,
                        const float* __restrict__ W_key,
                        const float* __restrict__ W_q,
                        const float* __restrict__ b_key,
                        const float* __restrict__ b_q,
                        float* __restrict__ WHT,
                        float* __restrict__ WK2T, float* __restrict__ bias2) {
  int i = blockIdx.x * 256 + threadIdx.x;
  if (i < HH * 52) {
    int j = i / 52, h = i % 52;
    WHT[i] = (h < HH) ? W_ctx[h * (2 * HH) + HH + j] : 0.f;
  }
  if (i < HH * 64) {
    int j = i >> 6, l = i & 63;
    float v = 0.f;
    if (l < HH) v = W_ctx[l * (2 * HH) + j];
    else if (l < HH + KK) v = W_key[(l - HH) * HH + j];
    else if (l < HH + 2 * KK) v = W_q[(l - HH - KK) * HH + j];
    WK2T[i] = v;
  }
  if (i < 64) {
    float bv = 0.f;
    if (i >= HH && i < HH + KK) bv = b_key[i - HH];
    else if (i >= HH + KK && i < HH + 2 * KK) bv = b_q[i - HH - KK];
    bias2[i] = bv;
  }
}

// ---------------- K1 (MFMA, fused): g = relu(x@W_in^T+b_in)@Wh^T + b_ctx ---
// R18/R22-verified. g stored f32 in chain layout g[(b*TT+t)*GST + gg].
__global__ __launch_bounds__(256, 2) void k1_mfma(
    const float* __restrict__ x, const float* __restrict__ W_in,
    const float* __restrict__ WHT, const float* __restrict__ b_in,
    const float* __restrict__ b_ctx, float* __restrict__ g) {
  const int lane = threadIdx.x & 63;
  const int wave = threadIdx.x >> 6;
  const int lrow = lane & 15, lgrp = lane >> 4;

#define WA1D(m, kk)                                                     \
  half4 wa1_##m##_##kk;                                                 \
  {                                                                     \
    const int hh = 16 * (m) + lrow;                                     \
    const int j0 = 16 * (kk) + 4 * lgrp;                                \
    const bool v = (hh < HH);                                           \
    const float* p = W_in + (size_t)(v ? hh : 0) * DD + j0;             \
    wa1_##m##_##kk[0] = (_Float16)(v ? p[0] : 0.f);                     \
    wa1_##m##_##kk[1] = (_Float16)(v ? p[1] : 0.f);                     \
    wa1_##m##_##kk[2] = (_Float16)(v ? p[2] : 0.f);                     \
    wa1_##m##_##kk[3] = (_Float16)(v ? p[3] : 0.f);                     \
  }
  WA1D(0, 0) WA1D(0, 1) WA1D(0, 2) WA1D(0, 3)
  WA1D(0, 4) WA1D(0, 5) WA1D(0, 6) WA1D(0, 7)
  WA1D(1, 0) WA1D(1, 1) WA1D(1, 2) WA1D(1, 3)
  WA1D(1, 4) WA1D(1, 5) WA1D(1, 6) WA1D(1, 7)
  WA1D(2, 0) WA1D(2, 1) WA1D(2, 2) WA1D(2, 3)
  WA1D(2, 4) WA1D(2, 5) WA1D(2, 6) WA1D(2, 7)
  WA1D(3, 0) WA1D(3, 1) WA1D(3, 2) WA1D(3, 3)
  WA1D(3, 4) WA1D(3, 5) WA1D(3, 6) WA1D(3, 7)

#define WA2D(m, kk)                                                     \
  half4 wa2_##m##_##kk;                                                 \
  {                                                                     \
    const int gg = 16 * (m) + lrow;                                     \
    const int h0 = 16 * (kk) + 4 * lgrp;                                \
    wa2_##m##_##kk[0] = (_Float16)((gg < HH && h0 + 0 < HH) ? WHT[(h0 + 0) * 52 + gg] : 0.f); \
    wa2_##m##_##kk[1] = (_Float16)((gg < HH && h0 + 1 < HH) ? WHT[(h0 + 1) * 52 + gg] : 0.f); \
    wa2_##m##_##kk[2] = (_Float16)((gg < HH && h0 + 2 < HH) ? WHT[(h0 + 2) * 52 + gg] : 0.f); \
    wa2_##m##_##kk[3] = (_Float16)((gg < HH && h0 + 3 < HH) ? WHT[(h0 + 3) * 52 + gg] : 0.f); \
  }
  WA2D(0, 0) WA2D(0, 1) WA2D(0, 2) WA2D(0, 3)
  WA2D(1, 0) WA2D(1, 1) WA2D(1, 2) WA2D(1, 3)
  WA2D(2, 0) WA2D(2, 1) WA2D(2, 2) WA2D(2, 3)
  WA2D(3, 0) WA2D(3, 1) WA2D(3, 2) WA2D(3, 3)

#define BDEF(m, r)                                                      \
  const float bin_##m##_##r =                                           \
      (16 * (m) + 4 * lgrp + (r) < HH) ? b_in[16 * (m) + 4 * lgrp + (r)] : 0.f; \
  const float bct_##m##_##r =                                           \
      (16 * (m) + 4 * lgrp + (r) < HH) ? b_ctx[16 * (m) + 4 * lgrp + (r)] : 0.f;
  BDEF(0, 0) BDEF(0, 1) BDEF(0, 2) BDEF(0, 3)
  BDEF(1, 0) BDEF(1, 1) BDEF(1, 2) BDEF(1, 3)
  BDEF(2, 0) BDEF(2, 1) BDEF(2, 2) BDEF(2, 3)
  BDEF(3, 0) BDEF(3, 1) BDEF(3, 2) BDEF(3, 3)

  const f32x4 zf = {0.f, 0.f, 0.f, 0.f};

#pragma unroll 1
  for (int it = 0; it < 4; ++it) {
    const int tile = (blockIdx.x * 4 + wave) * 4 + it;
    const int row = tile * 16 + lrow;
    const float* __restrict__ xr = x + (size_t)row * DD + 4 * lgrp;

#define XLD(kk)                                                         \
  half4 xb##kk;                                                         \
  {                                                                     \
    const float4 xv = *reinterpret_cast<const float4*>(xr + 16 * kk);   \
    xb##kk[0] = (_Float16)xv.x;                                         \
    xb##kk[1] = (_Float16)xv.y;                                         \
    xb##kk[2] = (_Float16)xv.z;                                         \
    xb##kk[3] = (_Float16)xv.w;                                         \
  }
    XLD(0) XLD(1) XLD(2) XLD(3) XLD(4) XLD(5) XLD(6) XLD(7)

    f32x4 d10 = zf, d11 = zf, d12 = zf, d13 = zf;
#define MM1(kk)                                                              \
  d10 = __builtin_amdgcn_mfma_f32_16x16x16f16(wa1_0_##kk, xb##kk, d10, 0, 0, 0); \
  d11 = __builtin_amdgcn_mfma_f32_16x16x16f16(wa1_1_##kk, xb##kk, d11, 0, 0, 0); \
  d12 = __builtin_amdgcn_mfma_f32_16x16x16f16(wa1_2_##kk, xb##kk, d12, 0, 0, 0); \
  d13 = __builtin_amdgcn_mfma_f32_16x16x16f16(wa1_3_##kk, xb##kk, d13, 0, 0, 0);
    MM1(0) MM1(1) MM1(2) MM1(3) MM1(4) MM1(5) MM1(6) MM1(7)

#define HBD(k)                                                    \
  half4 hb##k;                                                    \
  hb##k[0] = (_Float16)fmaxf(d1##k[0] + bin_##k##_0, 0.f);        \
  hb##k[1] = (_Float16)fmaxf(d1##k[1] + bin_##k##_1, 0.f);        \
  hb##k[2] = (_Float16)fmaxf(d1##k[2] + bin_##k##_2, 0.f);        \
  hb##k[3] = (_Float16)fmaxf(d1##k[3] + bin_##k##_3, 0.f);
    HBD(0) HBD(1) HBD(2) HBD(3)

    f32x4 d20 = zf, d21 = zf, d22 = zf, d23 = zf;
#define MM2(kk)                                                              \
  d20 = __builtin_amdgcn_mfma_f32_16x16x16f16(wa2_0_##kk, hb##kk, d20, 0, 0, 0); \
  d21 = __builtin_amdgcn_mfma_f32_16x16x16f16(wa2_1_##kk, hb##kk, d21, 0, 0, 0); \
  d22 = __builtin_amdgcn_mfma_f32_16x16x16f16(wa2_2_##kk, hb##kk, d22, 0, 0, 0); \
  d23 = __builtin_amdgcn_mfma_f32_16x16x16f16(wa2_3_##kk, hb##kk, d23, 0, 0, 0);
    MM2(0) MM2(1) MM2(2) MM2(3)

    float* __restrict__ gr =
        g + ((size_t)(row & (BB - 1)) * TT + (row >> 9)) * GST;
    *reinterpret_cast<float4*>(gr + 4 * lgrp) =
        make_float4(d20[0] + bct_0_0, d20[1] + bct_0_1, d20[2] + bct_0_2,
                    d20[3] + bct_0_3);
    *reinterpret_cast<float4*>(gr + 16 + 4 * lgrp) =
        make_float4(d21[0] + bct_1_0, d21[1] + bct_1_1, d21[2] + bct_1_2,
                    d21[3] + bct_1_3);
    *reinterpret_cast<float4*>(gr + 32 + 4 * lgrp) =
        make_float4(d22[0] + bct_2_0, d22[1] + bct_2_1, d22[2] + bct_2_2,
                    d22[3] + bct_2_3);
    if (lgrp == 0) {
      *reinterpret_cast<float4*>(gr + 48) =
          make_float4(d23[0] + bct_3_0, d23[1] + bct_3_1, 0.f, 0.f);
    }
  }
}

// ---------------- K23: fused recurrence + attention (512 blocks x 4 waves) -
// Wave 0: R22-verified scalar recurrence, egress to LDS f16 (ctx_l/kq_l),
// progress flag bumped every 16 steps (monotonic -> deadlock-free; in-wave
// DS ordering gives release semantics). Waves 1-3: k3-verified MFMA
// attention per 16-t tile, reading LDS directly (no staging, no barriers
// after init); rows beyond progress are zero-init -> finite -> masked 0x0.
// Epilogue in-register via shuffle reduce (no o_l).
__global__ __launch_bounds__(256, 2) void k23_fused(
    const float* __restrict__ g, const float* __restrict__ WK2T,
    const float* __restrict__ bias2, const float* __restrict__ fc,
    const float* __restrict__ W_act, const float* __restrict__ b_act,
    float* __restrict__ out) {
  __shared__ _Float16 ctx_l[272 * CXS];   // [s][h], h 50-65 stay 0
  __shared__ _Float16 kq_l[272 * KQR2];   // [s][k], k 10-17 stay 0
  __shared__ __align__(16) float c_lds[64];
  __shared__ int prog;

  const int tid = threadIdx.x;
  const int b = blockIdx.x;
  const int wv = tid >> 6;
  const int lane = tid & 63;

  for (int i = tid; i < 272 * CXS; i += 256) ctx_l[i] = (_Float16)0.f;
  for (int i = tid; i < 272 * KQR2; i += 256) kq_l[i] = (_Float16)0.f;
  if (tid == 0) prog = 0;
  __syncthreads();

  if (wv == 0) {
    // ================= recurrence (wave 0) =================
#define WDECL(j)                            \
  float w##j = WK2T[(j) * 64 + lane];       \
  asm volatile("" : "+v"(w##j));
    R50(WDECL)
    const float wz = 0.f;
    const float bias = bias2[lane];

    const float c0v = (lane < HH) ? fc[lane] : 0.f;
    c_lds[lane] = (lane < HH) ? c0v : 0.f;
    if (lane < HH) ctx_l[0 * CXS + lane] = (_Float16)c0v;

    const int gslot = (lane < GST) ? lane : (GST - 1);
    const float* __restrict__ gbp = g + (size_t)b * TT * GST + gslot;
    float gq0 = gbp[0 * GST];
    float gq1 = gbp[1 * GST];
    float gq2 = gbp[2 * GST];
    float gq3 = gbp[3 * GST];

#define KQ(J, wa, wb, wc, wd)                                            \
  {                                                                      \
    const float4 cq = *reinterpret_cast<const float4*>(&c_lds[J]);       \
    acc0 = fmaf(wa, cq.x, acc0);                                         \
    acc1 = fmaf(wb, cq.y, acc1);                                         \
    acc2 = fmaf(wc, cq.z, acc2);                                         \
    acc3 = fmaf(wd, cq.w, acc3);                                         \
  }
#define DOT50R                                                           \
  float acc0 = 0.f, acc1 = 0.f, acc2 = 0.f, acc3 = 0.f;                  \
  KQ(0, w0, w1, w2, w3) KQ(4, w4, w5, w6, w7)                            \
  KQ(8, w8, w9, w10, w11) KQ(12, w12, w13, w14, w15)                     \
  KQ(16, w16, w17, w18, w19) KQ(20, w20, w21, w22, w23)                  \
  KQ(24, w24, w25, w26, w27) KQ(28, w28, w29, w30, w31)                  \
  KQ(32, w32, w33, w34, w35) KQ(36, w36, w37, w38, w39)                  \
  KQ(40, w40, w41, w42, w43) KQ(44, w44, w45, w46, w47)                  \
  KQ(48, w48, w49, wz, wz)                                               \
  const float acc = (acc0 + acc1) + (acc2 + acc3);

#define BODYF(RR, GQ)                                                    \
  {                                                                      \
    const int t = tg4 + RR;                                              \
    DOT50R                                                               \
    if (lane >= HH) kq_l[t * KQR2 + (lane - HH)] = (_Float16)(acc + bias); \
    const float cn = fmaxf(acc + GQ, 0.f);                               \
    GQ = gbp[(size_t)min(t + 4, TT - 1) * GST];                          \
    if (lane < HH) {                                                     \
      ctx_l[(t + 1) * CXS + lane] = (_Float16)cn;                        \
      c_lds[lane] = cn;                                                  \
    }                                                                    \
  }

#pragma unroll 1
    for (int tg4 = 0; tg4 < TT; tg4 += 4) {
      BODYF(0, gq0) BODYF(1, gq1) BODYF(2, gq2) BODYF(3, gq3)
      if ((tg4 & 12) == 12) {  // every 16 steps
        asm volatile("" ::: "memory");
        if (lane == 0) *((volatile int*)&prog) = tg4 + 4;
      }
    }

    {  // tail: key/q of c_TT at index TT (=256)
      DOT50R
      if (lane >= HH) kq_l[TT * KQR2 + (lane - HH)] = (_Float16)(acc + bias);
    }
    asm volatile("" ::: "memory");
    if (lane == 0) *((volatile int*)&prog) = 257;

  } else {
    // ================= attention (waves 1-3) =================
    const int lrow = lane & 15, lgrp = lane >> 4;
    const f32x4 zf = {0.f, 0.f, 0.f, 0.f};

#define WACT(a, ht)                                                     \
  const float wa_##a##_##ht =                                           \
      (lrow + 16 * (ht) < HH) ? W_act[(a)*HH + lrow + 16 * (ht)] : 0.f;
    WACT(0, 0) WACT(0, 1) WACT(0, 2) WACT(0, 3)
    WACT(1, 0) WACT(1, 1) WACT(1, 2) WACT(1, 3)
    WACT(2, 0) WACT(2, 1) WACT(2, 2) WACT(2, 3)
    WACT(3, 0) WACT(3, 1) WACT(3, 2) WACT(3, 3)
    const float ba0 = b_act[0], ba1 = b_act[1];
    const float ba2 = b_act[2], ba3 = b_act[3];

#pragma unroll 1
    for (int k = wv - 1; k < 16; k += 3) {
      const int tw = k * 16;
      const int need = (tw + 17 > 257) ? 257 : (tw + 17);
      while (*((volatile int*)&prog) < need) __builtin_amdgcn_s_sleep(8);
      asm volatile("" ::: "memory");

      half4 qf;
#pragma unroll
      for (int i = 0; i < 4; ++i) {
        const int kk = 4 * lgrp + i;
        qf[i] = (kk < KK) ? kq_l[(tw + lrow + 1) * KQR2 + 5 + kk]
                          : (_Float16)0.f;
      }

      f32x4 oa0 = zf, oa1 = zf, oa2 = zf, oa3 = zf;
      float su = 0.f;

#pragma unroll 1
      for (int sb = 0; sb <= tw + 16; sb += 16) {
        half4 kf;
#pragma unroll
        for (int i = 0; i < 4; ++i)
          kf[i] = kq_l[(sb + lrow) * KQR2 + 4 * lgrp + i];

        const f32x4 sc =
            __builtin_amdgcn_mfma_f32_16x16x16f16(kf, qf, zf, 0, 0, 0);

        half4 pa;
#pragma unroll
        for (int r = 0; r < 4; ++r) {
          const int s = sb + 4 * lgrp + r;
          const float p = (s <= tw + lrow + 1) ? __expf(sc[r]) : 0.f;
          su += p;
          pa[r] = (_Float16)p;
        }

        const int vb = sb + 4 * lgrp;
#define PVF(HT, ACC)                                                      \
  {                                                                       \
    half4 vf;                                                             \
    vf[0] = ctx_l[(vb + 0) * CXS + lrow + 16 * HT];                       \
    vf[1] = ctx_l[(vb + 1) * CXS + lrow + 16 * HT];                       \
    vf[2] = ctx_l[(vb + 2) * CXS + lrow + 16 * HT];                       \
    vf[3] = ctx_l[(vb + 3) * CXS + lrow + 16 * HT];                       \
    ACC = __builtin_amdgcn_mfma_f32_16x16x16f16(pa, vf, ACC, 0, 0, 0);    \
  }
        PVF(0, oa0) PVF(1, oa1) PVF(2, oa2) PVF(3, oa3)
      }

      // su total for t = tw + lrow (reduce over lgrp)
      su += __shfl_xor(su, 16, 64);
      su += __shfl_xor(su, 32, 64);

      // part(r,a) for t = tw + 4*lgrp + r; reduce over lrow
#define PTC(r)                                                                 \
  float pt##r##_0 = oa0[r] * wa_0_0 + oa1[r] * wa_0_1 + oa2[r] * wa_0_2 +      \
                    oa3[r] * wa_0_3;                                           \
  float pt##r##_1 = oa0[r] * wa_1_0 + oa1[r] * wa_1_1 + oa2[r] * wa_1_2 +      \
                    oa3[r] * wa_1_3;                                           \
  float pt##r##_2 = oa0[r] * wa_2_0 + oa1[r] * wa_2_1 + oa2[r] * wa_2_2 +      \
                    oa3[r] * wa_2_3;                                           \
  float pt##r##_3 = oa0[r] * wa_3_0 + oa1[r] * wa_3_1 + oa2[r] * wa_3_2 +      \
                    oa3[r] * wa_3_3;
      PTC(0) PTC(1) PTC(2) PTC(3)
#define REDX(v)                 \
  v += __shfl_xor(v, 1, 64);    \
  v += __shfl_xor(v, 2, 64);    \
  v += __shfl_xor(v, 4, 64);    \
  v += __shfl_xor(v, 8, 64);
      REDX(pt0_0) REDX(pt0_1) REDX(pt0_2) REDX(pt0_3)
      REDX(pt1_0) REDX(pt1_1) REDX(pt1_2) REDX(pt1_3)
      REDX(pt2_0) REDX(pt2_1) REDX(pt2_2) REDX(pt2_3)
      REDX(pt3_0) REDX(pt3_1) REDX(pt3_2) REDX(pt3_3)

#define EPI(r)                                                            \
  {                                                                       \
    const float sur = __shfl(su, 4 * lgrp + (r), 64);                     \
    if (lrow == 0) {                                                      \
      const float inv = 1.f / sur;                                        \
      const int t = tw + 4 * lgrp + (r);                                  \
      *reinterpret_cast<float4*>(out + ((size_t)t * BB + b) * AA) =       \
          make_float4(fmaf(pt##r##_0, inv, ba0), fmaf(pt##r##_1, inv, ba1), \
                      fmaf(pt##r##_2, inv, ba2), fmaf(pt##r##_3, inv, ba3)); \
    }                                                                     \
  }
      EPI(0) EPI(1) EPI(2) EPI(3)
    }
  }
}

extern "C" void kernel_launch(void* const* d_in, const int* in_sizes, int n_in,
                              void* d_out, int out_size, void* d_ws,
                              size_t ws_size, hipStream_t stream) {
  const float* x = (const float*)d_in[0];
  const float* W_in = (const float*)d_in[1];
  const float* b_in = (const float*)d_in[2];
  const float* W_ctx = (const float*)d_in[3];
  const float* b_ctx = (const float*)d_in[4];
  const float* W_key = (const float*)d_in[5];
  const float* b_key = (const float*)d_in[6];
  const float* W_q = (const float*)d_in[7];
  const float* b_q = (const float*)d_in[8];
  const float* fc = (const float*)d_in[9];
  const float* W_act = (const float*)d_in[10];
  const float* b_act = (const float*)d_in[11];
  float* out = (float*)d_out;
  float* ws = (float*)d_ws;

  float* WHT = ws;                                 // 50*52
  float* WK2T = ws + 4096;                         // 50*64
  float* bias2 = ws + 8128;                        // 64
  float* g = ws + 8192;                            // 131072*52
  // total ~27 MB

  hipLaunchKernelGGL(k0_prep, dim3(26), dim3(256), 0, stream, W_in, W_ctx,
                     W_key, W_q, b_key, b_q, WHT, WK2T, bias2);
  hipLaunchKernelGGL(k1_mfma, dim3(512), dim3(256), 0, stream, x, W_in, WHT,
                     b_in, b_ctx, g);
  hipLaunchKernelGGL(k23_fused, dim3(512), dim3(256), 0, stream, g, WK2T,
                     bias2, fc, W_act, b_act, out);
}

// Round 24
// 142.387 us; speedup vs baseline: 1.5897x; 1.0186x over previous
//
#include <hip/hip_runtime.h>

#define TT 256
#define BB 512
#define DD 128
#define HH 50
#define KK 5
#define AA 4
#define NROW 131072
#define GST 52           // g row stride (16B-aligned float4 slots)
#define CXS 66           // ctx_l row stride (f16)
#define KQR2 18          // kq_l row stride (f16)

#define R50(X) X(0) X(1) X(2) X(3) X(4) X(5) X(6) X(7) X(8) X(9) \
  X(10) X(11) X(12) X(13) X(14) X(15) X(16) X(17) X(18) X(19) \
  X(20) X(21) X(22) X(23) X(24) X(25) X(26) X(27) X(28) X(29) \
  X(30) X(31) X(32) X(33) X(34) X(35) X(36) X(37) X(38) X(39) \
  X(40) X(41) X(42) X(43) X(44) X(45) X(46) X(47) X(48) X(49)

typedef _Float16 half4 __attribute__((ext_vector_type(4)));
typedef float f32x4 __attribute__((ext_vector_type(4)));

// ---------------- K0: weight prep ----------------
__global__ void k0_prep(const float* __restrict__ W_in,
                        const float* __restrict__ W_ctx,
                        const float* __restrict__ W_key,
                        const float* __restrict__ W_q,
                        const float* __restrict__ b_key,
                        const float* __restrict__ b_q,
                        float* __restrict__ WHT,
                        float* __restrict__ WK2T, float* __restrict__ bias2) {
  int i = blockIdx.x * 256 + threadIdx.x;
  if (i < HH * 52) {
    int j = i / 52, h = i % 52;
    WHT[i] = (h < HH) ? W_ctx[h * (2 * HH) + HH + j] : 0.f;
  }
  if (i < HH * 64) {
    int j = i >> 6, l = i & 63;
    float v = 0.f;
    if (l < HH) v = W_ctx[l * (2 * HH) + j];
    else if (l < HH + KK) v = W_key[(l - HH) * HH + j];
    else if (l < HH + 2 * KK) v = W_q[(l - HH - KK) * HH + j];
    WK2T[i] = v;
  }
  if (i < 64) {
    float bv = 0.f;
    if (i >= HH && i < HH + KK) bv = b_key[i - HH];
    else if (i >= HH + KK && i < HH + 2 * KK) bv = b_q[i - HH - KK];
    bias2[i] = bv;
  }
}

// ---------------- K1 (MFMA, fused): g = relu(x@W_in^T+b_in)@Wh^T + b_ctx ---
// R18/R22-verified. g stored f32 in chain layout g[(b*TT+t)*GST + gg].
__global__ __launch_bounds__(256, 2) void k1_mfma(
    const float* __restrict__ x, const float* __restrict__ W_in,
    const float* __restrict__ WHT, const float* __restrict__ b_in,
    const float* __restrict__ b_ctx, float* __restrict__ g) {
  const int lane = threadIdx.x & 63;
  const int wave = threadIdx.x >> 6;
  const int lrow = lane & 15, lgrp = lane >> 4;

#define WA1D(m, kk)                                                     \
  half4 wa1_##m##_##kk;                                                 \
  {                                                                     \
    const int hh = 16 * (m) + lrow;                                     \
    const int j0 = 16 * (kk) + 4 * lgrp;                                \
    const bool v = (hh < HH);                                           \
    const float* p = W_in + (size_t)(v ? hh : 0) * DD + j0;             \
    wa1_##m##_##kk[0] = (_Float16)(v ? p[0] : 0.f);                     \
    wa1_##m##_##kk[1] = (_Float16)(v ? p[1] : 0.f);                     \
    wa1_##m##_##kk[2] = (_Float16)(v ? p[2] : 0.f);                     \
    wa1_##m##_##kk[3] = (_Float16)(v ? p[3] : 0.f);                     \
  }
  WA1D(0, 0) WA1D(0, 1) WA1D(0, 2) WA1D(0, 3)
  WA1D(0, 4) WA1D(0, 5) WA1D(0, 6) WA1D(0, 7)
  WA1D(1, 0) WA1D(1, 1) WA1D(1, 2) WA1D(1, 3)
  WA1D(1, 4) WA1D(1, 5) WA1D(1, 6) WA1D(1, 7)
  WA1D(2, 0) WA1D(2, 1) WA1D(2, 2) WA1D(2, 3)
  WA1D(2, 4) WA1D(2, 5) WA1D(2, 6) WA1D(2, 7)
  WA1D(3, 0) WA1D(3, 1) WA1D(3, 2) WA1D(3, 3)
  WA1D(3, 4) WA1D(3, 5) WA1D(3, 6) WA1D(3, 7)

#define WA2D(m, kk)                                                     \
  half4 wa2_##m##_##kk;                                                 \
  {                                                                     \
    const int gg = 16 * (m) + lrow;                                     \
    const int h0 = 16 * (kk) + 4 * lgrp;                                \
    wa2_##m##_##kk[0] = (_Float16)((gg < HH && h0 + 0 < HH) ? WHT[(h0 + 0) * 52 + gg] : 0.f); \
    wa2_##m##_##kk[1] = (_Float16)((gg < HH && h0 + 1 < HH) ? WHT[(h0 + 1) * 52 + gg] : 0.f); \
    wa2_##m##_##kk[2] = (_Float16)((gg < HH && h0 + 2 < HH) ? WHT[(h0 + 2) * 52 + gg] : 0.f); \
    wa2_##m##_##kk[3] = (_Float16)((gg < HH && h0 + 3 < HH) ? WHT[(h0 + 3) * 52 + gg] : 0.f); \
  }
  WA2D(0, 0) WA2D(0, 1) WA2D(0, 2) WA2D(0, 3)
  WA2D(1, 0) WA2D(1, 1) WA2D(1, 2) WA2D(1, 3)
  WA2D(2, 0) WA2D(2, 1) WA2D(2, 2) WA2D(2, 3)
  WA2D(3, 0) WA2D(3, 1) WA2D(3, 2) WA2D(3, 3)

#define BDEF(m, r)                                                      \
  const float bin_##m##_##r =                                           \
      (16 * (m) + 4 * lgrp + (r) < HH) ? b_in[16 * (m) + 4 * lgrp + (r)] : 0.f; \
  const float bct_##m##_##r =                                           \
      (16 * (m) + 4 * lgrp + (r) < HH) ? b_ctx[16 * (m) + 4 * lgrp + (r)] : 0.f;
  BDEF(0, 0) BDEF(0, 1) BDEF(0, 2) BDEF(0, 3)
  BDEF(1, 0) BDEF(1, 1) BDEF(1, 2) BDEF(1, 3)
  BDEF(2, 0) BDEF(2, 1) BDEF(2, 2) BDEF(2, 3)
  BDEF(3, 0) BDEF(3, 1) BDEF(3, 2) BDEF(3, 3)

  const f32x4 zf = {0.f, 0.f, 0.f, 0.f};

#pragma unroll 1
  for (int it = 0; it < 4; ++it) {
    const int tile = (blockIdx.x * 4 + wave) * 4 + it;
    const int row = tile * 16 + lrow;
    const float* __restrict__ xr = x + (size_t)row * DD + 4 * lgrp;

#define XLD(kk)                                                         \
  half4 xb##kk;                                                         \
  {                                                                     \
    const float4 xv = *reinterpret_cast<const float4*>(xr + 16 * kk);   \
    xb##kk[0] = (_Float16)xv.x;                                         \
    xb##kk[1] = (_Float16)xv.y;                                         \
    xb##kk[2] = (_Float16)xv.z;                                         \
    xb##kk[3] = (_Float16)xv.w;                                         \
  }
    XLD(0) XLD(1) XLD(2) XLD(3) XLD(4) XLD(5) XLD(6) XLD(7)

    f32x4 d10 = zf, d11 = zf, d12 = zf, d13 = zf;
#define MM1(kk)                                                              \
  d10 = __builtin_amdgcn_mfma_f32_16x16x16f16(wa1_0_##kk, xb##kk, d10, 0, 0, 0); \
  d11 = __builtin_amdgcn_mfma_f32_16x16x16f16(wa1_1_##kk, xb##kk, d11, 0, 0, 0); \
  d12 = __builtin_amdgcn_mfma_f32_16x16x16f16(wa1_2_##kk, xb##kk, d12, 0, 0, 0); \
  d13 = __builtin_amdgcn_mfma_f32_16x16x16f16(wa1_3_##kk, xb##kk, d13, 0, 0, 0);
    MM1(0) MM1(1) MM1(2) MM1(3) MM1(4) MM1(5) MM1(6) MM1(7)

#define HBD(k)                                                    \
  half4 hb##k;                                                    \
  hb##k[0] = (_Float16)fmaxf(d1##k[0] + bin_##k##_0, 0.f);        \
  hb##k[1] = (_Float16)fmaxf(d1##k[1] + bin_##k##_1, 0.f);        \
  hb##k[2] = (_Float16)fmaxf(d1##k[2] + bin_##k##_2, 0.f);        \
  hb##k[3] = (_Float16)fmaxf(d1##k[3] + bin_##k##_3, 0.f);
    HBD(0) HBD(1) HBD(2) HBD(3)

    f32x4 d20 = zf, d21 = zf, d22 = zf, d23 = zf;
#define MM2(kk)                                                              \
  d20 = __builtin_amdgcn_mfma_f32_16x16x16f16(wa2_0_##kk, hb##kk, d20, 0, 0, 0); \
  d21 = __builtin_amdgcn_mfma_f32_16x16x16f16(wa2_1_##kk, hb##kk, d21, 0, 0, 0); \
  d22 = __builtin_amdgcn_mfma_f32_16x16x16f16(wa2_2_##kk, hb##kk, d22, 0, 0, 0); \
  d23 = __builtin_amdgcn_mfma_f32_16x16x16f16(wa2_3_##kk, hb##kk, d23, 0, 0, 0);
    MM2(0) MM2(1) MM2(2) MM2(3)

    float* __restrict__ gr =
        g + ((size_t)(row & (BB - 1)) * TT + (row >> 9)) * GST;
    *reinterpret_cast<float4*>(gr + 4 * lgrp) =
        make_float4(d20[0] + bct_0_0, d20[1] + bct_0_1, d20[2] + bct_0_2,
                    d20[3] + bct_0_3);
    *reinterpret_cast<float4*>(gr + 16 + 4 * lgrp) =
        make_float4(d21[0] + bct_1_0, d21[1] + bct_1_1, d21[2] + bct_1_2,
                    d21[3] + bct_1_3);
    *reinterpret_cast<float4*>(gr + 32 + 4 * lgrp) =
        make_float4(d22[0] + bct_2_0, d22[1] + bct_2_1, d22[2] + bct_2_2,
                    d22[3] + bct_2_3);
    if (lgrp == 0) {
      *reinterpret_cast<float4*>(gr + 48) =
          make_float4(d23[0] + bct_3_0, d23[1] + bct_3_1, 0.f, 0.f);
    }
  }
}

// ---------------- K23: fused recurrence + attention (512 blocks x 4 waves) -
// R23-verified structure. R24: recurrence wave runs at s_setprio(3) so its
// serial dependence chain wins every CU scheduler arbitration against the
// consumer waves (producer/consumer role split = T5's regime); consumers
// poll with a longer s_sleep; progress published every 8 steps.
__global__ __launch_bounds__(256, 2) void k23_fused(
    const float* __restrict__ g, const float* __restrict__ WK2T,
    const float* __restrict__ bias2, const float* __restrict__ fc,
    const float* __restrict__ W_act, const float* __restrict__ b_act,
    float* __restrict__ out) {
  __shared__ _Float16 ctx_l[272 * CXS];   // [s][h], h 50-65 stay 0
  __shared__ _Float16 kq_l[272 * KQR2];   // [s][k], junk k>=10 never used
  __shared__ __align__(16) float c_lds[64];
  __shared__ int prog;

  const int tid = threadIdx.x;
  const int b = blockIdx.x;
  const int wv = tid >> 6;
  const int lane = tid & 63;

  for (int i = tid; i < 272 * CXS; i += 256) ctx_l[i] = (_Float16)0.f;
  for (int i = tid; i < 272 * KQR2; i += 256) kq_l[i] = (_Float16)0.f;
  if (tid == 0) prog = 0;
  __syncthreads();

  if (wv == 0) {
    // ================= recurrence (wave 0), HIGH PRIORITY =================
    __builtin_amdgcn_s_setprio(3);
#define WDECL(j)                            \
  float w##j = WK2T[(j) * 64 + lane];       \
  asm volatile("" : "+v"(w##j));
    R50(WDECL)
    const float wz = 0.f;
    const float bias = bias2[lane];

    const float c0v = (lane < HH) ? fc[lane] : 0.f;
    c_lds[lane] = (lane < HH) ? c0v : 0.f;
    if (lane < HH) ctx_l[0 * CXS + lane] = (_Float16)c0v;

    const int gslot = (lane < GST) ? lane : (GST - 1);
    const float* __restrict__ gbp = g + (size_t)b * TT * GST + gslot;
    float gq0 = gbp[0 * GST];
    float gq1 = gbp[1 * GST];
    float gq2 = gbp[2 * GST];
    float gq3 = gbp[3 * GST];

#define KQ(J, wa, wb, wc, wd)                                            \
  {                                                                      \
    const float4 cq = *reinterpret_cast<const float4*>(&c_lds[J]);       \
    acc0 = fmaf(wa, cq.x, acc0);                                         \
    acc1 = fmaf(wb, cq.y, acc1);                                         \
    acc2 = fmaf(wc, cq.z, acc2);                                         \
    acc3 = fmaf(wd, cq.w, acc3);                                         \
  }
#define DOT50R                                                           \
  float acc0 = 0.f, acc1 = 0.f, acc2 = 0.f, acc3 = 0.f;                  \
  KQ(0, w0, w1, w2, w3) KQ(4, w4, w5, w6, w7)                            \
  KQ(8, w8, w9, w10, w11) KQ(12, w12, w13, w14, w15)                     \
  KQ(16, w16, w17, w18, w19) KQ(20, w20, w21, w22, w23)                  \
  KQ(24, w24, w25, w26, w27) KQ(28, w28, w29, w30, w31)                  \
  KQ(32, w32, w33, w34, w35) KQ(36, w36, w37, w38, w39)                  \
  KQ(40, w40, w41, w42, w43) KQ(44, w44, w45, w46, w47)                  \
  KQ(48, w48, w49, wz, wz)                                               \
  const float acc = (acc0 + acc1) + (acc2 + acc3);

#define BODYF(RR, GQ)                                                    \
  {                                                                      \
    const int t = tg4 + RR;                                              \
    DOT50R                                                               \
    if (lane >= HH) kq_l[t * KQR2 + (lane - HH)] = (_Float16)(acc + bias); \
    const float cn = fmaxf(acc + GQ, 0.f);                               \
    GQ = gbp[(size_t)min(t + 4, TT - 1) * GST];                          \
    if (lane < HH) {                                                     \
      ctx_l[(t + 1) * CXS + lane] = (_Float16)cn;                        \
      c_lds[lane] = cn;                                                  \
    }                                                                    \
  }

#pragma unroll 1
    for (int tg4 = 0; tg4 < TT; tg4 += 4) {
      BODYF(0, gq0) BODYF(1, gq1) BODYF(2, gq2) BODYF(3, gq3)
      if (tg4 & 4) {  // every 8 steps
        asm volatile("" ::: "memory");
        if (lane == 0) *((volatile int*)&prog) = tg4 + 4;
      }
    }

    {  // tail: key/q of c_TT at index TT (=256)
      DOT50R
      if (lane >= HH) kq_l[TT * KQR2 + (lane - HH)] = (_Float16)(acc + bias);
    }
    asm volatile("" ::: "memory");
    __builtin_amdgcn_s_setprio(0);
    if (lane == 0) *((volatile int*)&prog) = 257;

  } else {
    // ================= attention (waves 1-3), normal priority =============
    const int lrow = lane & 15, lgrp = lane >> 4;
    const f32x4 zf = {0.f, 0.f, 0.f, 0.f};

#define WACT(a, ht)                                                     \
  const float wa_##a##_##ht =                                           \
      (lrow + 16 * (ht) < HH) ? W_act[(a)*HH + lrow + 16 * (ht)] : 0.f;
    WACT(0, 0) WACT(0, 1) WACT(0, 2) WACT(0, 3)
    WACT(1, 0) WACT(1, 1) WACT(1, 2) WACT(1, 3)
    WACT(2, 0) WACT(2, 1) WACT(2, 2) WACT(2, 3)
    WACT(3, 0) WACT(3, 1) WACT(3, 2) WACT(3, 3)
    const float ba0 = b_act[0], ba1 = b_act[1];
    const float ba2 = b_act[2], ba3 = b_act[3];

#pragma unroll 1
    for (int k = wv - 1; k < 16; k += 3) {
      const int tw = k * 16;
      const int need = (tw + 17 > 257) ? 257 : (tw + 17);
      while (*((volatile int*)&prog) < need) __builtin_amdgcn_s_sleep(32);
      asm volatile("" ::: "memory");

      half4 qf;
#pragma unroll
      for (int i = 0; i < 4; ++i) {
        const int kk = 4 * lgrp + i;
        qf[i] = (kk < KK) ? kq_l[(tw + lrow + 1) * KQR2 + 5 + kk]
                          : (_Float16)0.f;
      }

      f32x4 oa0 = zf, oa1 = zf, oa2 = zf, oa3 = zf;
      float su = 0.f;

#pragma unroll 1
      for (int sb = 0; sb <= tw + 16; sb += 16) {
        half4 kf;
#pragma unroll
        for (int i = 0; i < 4; ++i)
          kf[i] = kq_l[(sb + lrow) * KQR2 + 4 * lgrp + i];

        const f32x4 sc =
            __builtin_amdgcn_mfma_f32_16x16x16f16(kf, qf, zf, 0, 0, 0);

        half4 pa;
#pragma unroll
        for (int r = 0; r < 4; ++r) {
          const int s = sb + 4 * lgrp + r;
          const float p = (s <= tw + lrow + 1) ? __expf(sc[r]) : 0.f;
          su += p;
          pa[r] = (_Float16)p;
        }

        const int vb = sb + 4 * lgrp;
#define PVF(HT, ACC)                                                      \
  {                                                                       \
    half4 vf;                                                             \
    vf[0] = ctx_l[(vb + 0) * CXS + lrow + 16 * HT];                       \
    vf[1] = ctx_l[(vb + 1) * CXS + lrow + 16 * HT];                       \
    vf[2] = ctx_l[(vb + 2) * CXS + lrow + 16 * HT];                       \
    vf[3] = ctx_l[(vb + 3) * CXS + lrow + 16 * HT];                       \
    ACC = __builtin_amdgcn_mfma_f32_16x16x16f16(pa, vf, ACC, 0, 0, 0);    \
  }
        PVF(0, oa0) PVF(1, oa1) PVF(2, oa2) PVF(3, oa3)
      }

      su += __shfl_xor(su, 16, 64);
      su += __shfl_xor(su, 32, 64);

#define PTC(r)                                                                 \
  float pt##r##_0 = oa0[r] * wa_0_0 + oa1[r] * wa_0_1 + oa2[r] * wa_0_2 +      \
                    oa3[r] * wa_0_3;                                           \
  float pt##r##_1 = oa0[r] * wa_1_0 + oa1[r] * wa_1_1 + oa2[r] * wa_1_2 +      \
                    oa3[r] * wa_1_3;                                           \
  float pt##r##_2 = oa0[r] * wa_2_0 + oa1[r] * wa_2_1 + oa2[r] * wa_2_2 +      \
                    oa3[r] * wa_2_3;                                           \
  float pt##r##_3 = oa0[r] * wa_3_0 + oa1[r] * wa_3_1 + oa2[r] * wa_3_2 +      \
                    oa3[r] * wa_3_3;
      PTC(0) PTC(1) PTC(2) PTC(3)
#define REDX(v)                 \
  v += __shfl_xor(v, 1, 64);    \
  v += __shfl_xor(v, 2, 64);    \
  v += __shfl_xor(v, 4, 64);    \
  v += __shfl_xor(v, 8, 64);
      REDX(pt0_0) REDX(pt0_1) REDX(pt0_2) REDX(pt0_3)
      REDX(pt1_0) REDX(pt1_1) REDX(pt1_2) REDX(pt1_3)
      REDX(pt2_0) REDX(pt2_1) REDX(pt2_2) REDX(pt2_3)
      REDX(pt3_0) REDX(pt3_1) REDX(pt3_2) REDX(pt3_3)

#define EPI(r)                                                            \
  {                                                                       \
    const float sur = __shfl(su, 4 * lgrp + (r), 64);                     \
    if (lrow == 0) {                                                      \
      const float inv = 1.f / sur;                                        \
      const int t = tw + 4 * lgrp + (r);                                  \
      *reinterpret_cast<float4*>(out + ((size_t)t * BB + b) * AA) =       \
          make_float4(fmaf(pt##r##_0, inv, ba0), fmaf(pt##r##_1, inv, ba1), \
                      fmaf(pt##r##_2, inv, ba2), fmaf(pt##r##_3, inv, ba3)); \
    }                                                                     \
  }
      EPI(0) EPI(1) EPI(2) EPI(3)
    }
  }
}

extern "C" void kernel_launch(void* const* d_in, const int* in_sizes, int n_in,
                              void* d_out, int out_size, void* d_ws,
                              size_t ws_size, hipStream_t stream) {
  const float* x = (const float*)d_in[0];
  const float* W_in = (const float*)d_in[1];
  const float* b_in = (const float*)d_in[2];
  const float* W_ctx = (const float*)d_in[3];
  const float* b_ctx = (const float*)d_in[4];
  const float* W_key = (const float*)d_in[5];
  const float* b_key = (const float*)d_in[6];
  const float* W_q = (const float*)d_in[7];
  const float* b_q = (const float*)d_in[8];
  const float* fc = (const float*)d_in[9];
  const float* W_act = (const float*)d_in[10];
  const float* b_act = (const float*)d_in[11];
  float* out = (float*)d_out;
  float* ws = (float*)d_ws;

  float* WHT = ws;                                 // 50*52
  float* WK2T = ws + 4096;                         // 50*64
  float* bias2 = ws + 8128;                        // 64
  float* g = ws + 8192;                            // 131072*52
  // total ~27 MB

  hipLaunchKernelGGL(k0_prep, dim3(26), dim3(256), 0, stream, W_in, W_ctx,
                     W_key, W_q, b_key, b_q, WHT, WK2T, bias2);
  hipLaunchKernelGGL(k1_mfma, dim3(512), dim3(256), 0, stream, x, W_in, WHT,
                     b_in, b_ctx, g);
  hipLaunchKernelGGL(k23_fused, dim3(512), dim3(256), 0, stream, g, WK2T,
                     bias2, fc, W_act, b_act, out);
}

// Round 25
// 140.736 us; speedup vs baseline: 1.6083x; 1.0117x over previous
//
#include <hip/hip_runtime.h>

#define TT 256
#define BB 512
#define DD 128
#define HH 50
#define KK 5
#define AA 4
#define NROW 131072
#define GST 52           // g row stride (16B-aligned float4 slots)
#define CXS2 276         // ctx_lT row stride (f16): 552B rows, 8B-aligned
#define KQS2 20          // kq_l row stride (f16): 40B rows, 8B-aligned

#define R50(X) X(0) X(1) X(2) X(3) X(4) X(5) X(6) X(7) X(8) X(9) \
  X(10) X(11) X(12) X(13) X(14) X(15) X(16) X(17) X(18) X(19) \
  X(20) X(21) X(22) X(23) X(24) X(25) X(26) X(27) X(28) X(29) \
  X(30) X(31) X(32) X(33) X(34) X(35) X(36) X(37) X(38) X(39) \
  X(40) X(41) X(42) X(43) X(44) X(45) X(46) X(47) X(48) X(49)

typedef _Float16 half4 __attribute__((ext_vector_type(4)));
typedef float f32x4 __attribute__((ext_vector_type(4)));

// ---------------- K0: weight prep ----------------
__global__ void k0_prep(const float* __restrict__ W_in,
                        const float* __restrict__ W_ctx,
                        const float* __restrict__ W_key,
                        const float* __restrict__ W_q,
                        const float* __restrict__ b_key,
                        const float* __restrict__ b_q,
                        float* __restrict__ WHT,
                        float* __restrict__ WK2T, float* __restrict__ bias2) {
  int i = blockIdx.x * 256 + threadIdx.x;
  if (i < HH * 52) {
    int j = i / 52, h = i % 52;
    WHT[i] = (h < HH) ? W_ctx[h * (2 * HH) + HH + j] : 0.f;
  }
  if (i < HH * 64) {
    int j = i >> 6, l = i & 63;
    float v = 0.f;
    if (l < HH) v = W_ctx[l * (2 * HH) + j];
    else if (l < HH + KK) v = W_key[(l - HH) * HH + j];
    else if (l < HH + 2 * KK) v = W_q[(l - HH - KK) * HH + j];
    WK2T[i] = v;
  }
  if (i < 64) {
    float bv = 0.f;
    if (i >= HH && i < HH + KK) bv = b_key[i - HH];
    else if (i >= HH + KK && i < HH + 2 * KK) bv = b_q[i - HH - KK];
    bias2[i] = bv;
  }
}

// ---------------- K1 (MFMA, fused): g = relu(x@W_in^T+b_in)@Wh^T + b_ctx ---
// R18/R22-verified. g stored f32 in chain layout g[(b*TT+t)*GST + gg].
__global__ __launch_bounds__(256, 2) void k1_mfma(
    const float* __restrict__ x, const float* __restrict__ W_in,
    const float* __restrict__ WHT, const float* __restrict__ b_in,
    const float* __restrict__ b_ctx, float* __restrict__ g) {
  const int lane = threadIdx.x & 63;
  const int wave = threadIdx.x >> 6;
  const int lrow = lane & 15, lgrp = lane >> 4;

#define WA1D(m, kk)                                                     \
  half4 wa1_##m##_##kk;                                                 \
  {                                                                     \
    const int hh = 16 * (m) + lrow;                                     \
    const int j0 = 16 * (kk) + 4 * lgrp;                                \
    const bool v = (hh < HH);                                           \
    const float* p = W_in + (size_t)(v ? hh : 0) * DD + j0;             \
    wa1_##m##_##kk[0] = (_Float16)(v ? p[0] : 0.f);                     \
    wa1_##m##_##kk[1] = (_Float16)(v ? p[1] : 0.f);                     \
    wa1_##m##_##kk[2] = (_Float16)(v ? p[2] : 0.f);                     \
    wa1_##m##_##kk[3] = (_Float16)(v ? p[3] : 0.f);                     \
  }
  WA1D(0, 0) WA1D(0, 1) WA1D(0, 2) WA1D(0, 3)
  WA1D(0, 4) WA1D(0, 5) WA1D(0, 6) WA1D(0, 7)
  WA1D(1, 0) WA1D(1, 1) WA1D(1, 2) WA1D(1, 3)
  WA1D(1, 4) WA1D(1, 5) WA1D(1, 6) WA1D(1, 7)
  WA1D(2, 0) WA1D(2, 1) WA1D(2, 2) WA1D(2, 3)
  WA1D(2, 4) WA1D(2, 5) WA1D(2, 6) WA1D(2, 7)
  WA1D(3, 0) WA1D(3, 1) WA1D(3, 2) WA1D(3, 3)
  WA1D(3, 4) WA1D(3, 5) WA1D(3, 6) WA1D(3, 7)

#define WA2D(m, kk)                                                     \
  half4 wa2_##m##_##kk;                                                 \
  {                                                                     \
    const int gg = 16 * (m) + lrow;                                     \
    const int h0 = 16 * (kk) + 4 * lgrp;                                \
    wa2_##m##_##kk[0] = (_Float16)((gg < HH && h0 + 0 < HH) ? WHT[(h0 + 0) * 52 + gg] : 0.f); \
    wa2_##m##_##kk[1] = (_Float16)((gg < HH && h0 + 1 < HH) ? WHT[(h0 + 1) * 52 + gg] : 0.f); \
    wa2_##m##_##kk[2] = (_Float16)((gg < HH && h0 + 2 < HH) ? WHT[(h0 + 2) * 52 + gg] : 0.f); \
    wa2_##m##_##kk[3] = (_Float16)((gg < HH && h0 + 3 < HH) ? WHT[(h0 + 3) * 52 + gg] : 0.f); \
  }
  WA2D(0, 0) WA2D(0, 1) WA2D(0, 2) WA2D(0, 3)
  WA2D(1, 0) WA2D(1, 1) WA2D(1, 2) WA2D(1, 3)
  WA2D(2, 0) WA2D(2, 1) WA2D(2, 2) WA2D(2, 3)
  WA2D(3, 0) WA2D(3, 1) WA2D(3, 2) WA2D(3, 3)

#define BDEF(m, r)                                                      \
  const float bin_##m##_##r =                                           \
      (16 * (m) + 4 * lgrp + (r) < HH) ? b_in[16 * (m) + 4 * lgrp + (r)] : 0.f; \
  const float bct_##m##_##r =                                           \
      (16 * (m) + 4 * lgrp + (r) < HH) ? b_ctx[16 * (m) + 4 * lgrp + (r)] : 0.f;
  BDEF(0, 0) BDEF(0, 1) BDEF(0, 2) BDEF(0, 3)
  BDEF(1, 0) BDEF(1, 1) BDEF(1, 2) BDEF(1, 3)
  BDEF(2, 0) BDEF(2, 1) BDEF(2, 2) BDEF(2, 3)
  BDEF(3, 0) BDEF(3, 1) BDEF(3, 2) BDEF(3, 3)

  const f32x4 zf = {0.f, 0.f, 0.f, 0.f};

#pragma unroll 1
  for (int it = 0; it < 4; ++it) {
    const int tile = (blockIdx.x * 4 + wave) * 4 + it;
    const int row = tile * 16 + lrow;
    const float* __restrict__ xr = x + (size_t)row * DD + 4 * lgrp;

#define XLD(kk)                                                         \
  half4 xb##kk;                                                         \
  {                                                                     \
    const float4 xv = *reinterpret_cast<const float4*>(xr + 16 * kk);   \
    xb##kk[0] = (_Float16)xv.x;                                         \
    xb##kk[1] = (_Float16)xv.y;                                         \
    xb##kk[2] = (_Float16)xv.z;                                         \
    xb##kk[3] = (_Float16)xv.w;                                         \
  }
    XLD(0) XLD(1) XLD(2) XLD(3) XLD(4) XLD(5) XLD(6) XLD(7)

    f32x4 d10 = zf, d11 = zf, d12 = zf, d13 = zf;
#define MM1(kk)                                                              \
  d10 = __builtin_amdgcn_mfma_f32_16x16x16f16(wa1_0_##kk, xb##kk, d10, 0, 0, 0); \
  d11 = __builtin_amdgcn_mfma_f32_16x16x16f16(wa1_1_##kk, xb##kk, d11, 0, 0, 0); \
  d12 = __builtin_amdgcn_mfma_f32_16x16x16f16(wa1_2_##kk, xb##kk, d12, 0, 0, 0); \
  d13 = __builtin_amdgcn_mfma_f32_16x16x16f16(wa1_3_##kk, xb##kk, d13, 0, 0, 0);
    MM1(0) MM1(1) MM1(2) MM1(3) MM1(4) MM1(5) MM1(6) MM1(7)

#define HBD(k)                                                    \
  half4 hb##k;                                                    \
  hb##k[0] = (_Float16)fmaxf(d1##k[0] + bin_##k##_0, 0.f);        \
  hb##k[1] = (_Float16)fmaxf(d1##k[1] + bin_##k##_1, 0.f);        \
  hb##k[2] = (_Float16)fmaxf(d1##k[2] + bin_##k##_2, 0.f);        \
  hb##k[3] = (_Float16)fmaxf(d1##k[3] + bin_##k##_3, 0.f);
    HBD(0) HBD(1) HBD(2) HBD(3)

    f32x4 d20 = zf, d21 = zf, d22 = zf, d23 = zf;
#define MM2(kk)                                                              \
  d20 = __builtin_amdgcn_mfma_f32_16x16x16f16(wa2_0_##kk, hb##kk, d20, 0, 0, 0); \
  d21 = __builtin_amdgcn_mfma_f32_16x16x16f16(wa2_1_##kk, hb##kk, d21, 0, 0, 0); \
  d22 = __builtin_amdgcn_mfma_f32_16x16x16f16(wa2_2_##kk, hb##kk, d22, 0, 0, 0); \
  d23 = __builtin_amdgcn_mfma_f32_16x16x16f16(wa2_3_##kk, hb##kk, d23, 0, 0, 0);
    MM2(0) MM2(1) MM2(2) MM2(3)

    float* __restrict__ gr =
        g + ((size_t)(row & (BB - 1)) * TT + (row >> 9)) * GST;
    *reinterpret_cast<float4*>(gr + 4 * lgrp) =
        make_float4(d20[0] + bct_0_0, d20[1] + bct_0_1, d20[2] + bct_0_2,
                    d20[3] + bct_0_3);
    *reinterpret_cast<float4*>(gr + 16 + 4 * lgrp) =
        make_float4(d21[0] + bct_1_0, d21[1] + bct_1_1, d21[2] + bct_1_2,
                    d21[3] + bct_1_3);
    *reinterpret_cast<float4*>(gr + 32 + 4 * lgrp) =
        make_float4(d22[0] + bct_2_0, d22[1] + bct_2_1, d22[2] + bct_2_2,
                    d22[3] + bct_2_3);
    if (lgrp == 0) {
      *reinterpret_cast<float4*>(gr + 48) =
          make_float4(d23[0] + bct_3_0, d23[1] + bct_3_1, 0.f, 0.f);
    }
  }
}

// ---------------- K23: fused recurrence + attention (512 blocks x 4 waves) -
// R24 structure + DS-traffic fix: ctx stored TRANSPOSED ctx_lT[h][s]
// (stride 276 f16; rows 8B-aligned, bank-spread) so the V-fragment is ONE
// ds_read_b64; kq rows stride 20 with keys@0-4, q@8-12 (slots 13-19 zero)
// so K/Q fragments are one b64 each. Consumer DS ops/subtile: 20 scalar
// u16 -> 5 b64 (2.8M bank conflicts measured in R24 came from the scalar
// strided reads contending on the shared DS pipe with the serial chain).
__global__ __launch_bounds__(256, 2) void k23_fused(
    const float* __restrict__ g, const float* __restrict__ WK2T,
    const float* __restrict__ bias2, const float* __restrict__ fc,
    const float* __restrict__ W_act, const float* __restrict__ b_act,
    float* __restrict__ out) {
  __shared__ _Float16 ctx_lT[64 * CXS2];  // [h][s], h>=50 rows stay 0
  __shared__ _Float16 kq_l[272 * KQS2];   // [s][slot]: k@0-4, q@8-12, else 0
  __shared__ __align__(16) float c_lds[64];
  __shared__ int prog;

  const int tid = threadIdx.x;
  const int b = blockIdx.x;
  const int wv = tid >> 6;
  const int lane = tid & 63;

  for (int i = tid; i < 64 * CXS2; i += 256) ctx_lT[i] = (_Float16)0.f;
  for (int i = tid; i < 272 * KQS2; i += 256) kq_l[i] = (_Float16)0.f;
  if (tid == 0) prog = 0;
  __syncthreads();

  if (wv == 0) {
    // ================= recurrence (wave 0), HIGH PRIORITY =================
    __builtin_amdgcn_s_setprio(3);
#define WDECL(j)                            \
  float w##j = WK2T[(j) * 64 + lane];       \
  asm volatile("" : "+v"(w##j));
    R50(WDECL)
    const float wz = 0.f;
    const float bias = bias2[lane];

    const float c0v = (lane < HH) ? fc[lane] : 0.f;
    c_lds[lane] = (lane < HH) ? c0v : 0.f;
    if (lane < HH) ctx_lT[lane * CXS2 + 0] = (_Float16)c0v;

    const int gslot = (lane < GST) ? lane : (GST - 1);
    const float* __restrict__ gbp = g + (size_t)b * TT * GST + gslot;
    float gq0 = gbp[0 * GST];
    float gq1 = gbp[1 * GST];
    float gq2 = gbp[2 * GST];
    float gq3 = gbp[3 * GST];

    const bool iskq = (lane >= HH && lane < HH + 2 * KK);
    const int kslot = iskq ? ((lane < HH + KK) ? lane - HH : lane - HH - KK + 8)
                           : 0;

#define KQ(J, wa, wb, wc, wd)                                            \
  {                                                                      \
    const float4 cq = *reinterpret_cast<const float4*>(&c_lds[J]);       \
    acc0 = fmaf(wa, cq.x, acc0);                                         \
    acc1 = fmaf(wb, cq.y, acc1);                                         \
    acc2 = fmaf(wc, cq.z, acc2);                                         \
    acc3 = fmaf(wd, cq.w, acc3);                                         \
  }
#define DOT50R                                                           \
  float acc0 = 0.f, acc1 = 0.f, acc2 = 0.f, acc3 = 0.f;                  \
  KQ(0, w0, w1, w2, w3) KQ(4, w4, w5, w6, w7)                            \
  KQ(8, w8, w9, w10, w11) KQ(12, w12, w13, w14, w15)                     \
  KQ(16, w16, w17, w18, w19) KQ(20, w20, w21, w22, w23)                  \
  KQ(24, w24, w25, w26, w27) KQ(28, w28, w29, w30, w31)                  \
  KQ(32, w32, w33, w34, w35) KQ(36, w36, w37, w38, w39)                  \
  KQ(40, w40, w41, w42, w43) KQ(44, w44, w45, w46, w47)                  \
  KQ(48, w48, w49, wz, wz)                                               \
  const float acc = (acc0 + acc1) + (acc2 + acc3);

#define BODYF(RR, GQ)                                                    \
  {                                                                      \
    const int t = tg4 + RR;                                              \
    DOT50R                                                               \
    if (iskq) kq_l[t * KQS2 + kslot] = (_Float16)(acc + bias);           \
    const float cn = fmaxf(acc + GQ, 0.f);                               \
    GQ = gbp[(size_t)min(t + 4, TT - 1) * GST];                          \
    if (lane < HH) {                                                     \
      ctx_lT[lane * CXS2 + (t + 1)] = (_Float16)cn;                      \
      c_lds[lane] = cn;                                                  \
    }                                                                    \
  }

#pragma unroll 1
    for (int tg4 = 0; tg4 < TT; tg4 += 4) {
      BODYF(0, gq0) BODYF(1, gq1) BODYF(2, gq2) BODYF(3, gq3)
      if (tg4 & 4) {  // every 8 steps
        asm volatile("" ::: "memory");
        if (lane == 0) *((volatile int*)&prog) = tg4 + 4;
      }
    }

    {  // tail: key/q of c_TT at index TT (=256)
      DOT50R
      if (iskq) kq_l[TT * KQS2 + kslot] = (_Float16)(acc + bias);
    }
    asm volatile("" ::: "memory");
    __builtin_amdgcn_s_setprio(0);
    if (lane == 0) *((volatile int*)&prog) = 257;

  } else {
    // ================= attention (waves 1-3), normal priority =============
    const int lrow = lane & 15, lgrp = lane >> 4;
    const f32x4 zf = {0.f, 0.f, 0.f, 0.f};

#define WACT(a, ht)                                                     \
  const float wa_##a##_##ht =                                           \
      (lrow + 16 * (ht) < HH) ? W_act[(a)*HH + lrow + 16 * (ht)] : 0.f;
    WACT(0, 0) WACT(0, 1) WACT(0, 2) WACT(0, 3)
    WACT(1, 0) WACT(1, 1) WACT(1, 2) WACT(1, 3)
    WACT(2, 0) WACT(2, 1) WACT(2, 2) WACT(2, 3)
    WACT(3, 0) WACT(3, 1) WACT(3, 2) WACT(3, 3)
    const float ba0 = b_act[0], ba1 = b_act[1];
    const float ba2 = b_act[2], ba3 = b_act[3];

#pragma unroll 1
    for (int k = wv - 1; k < 16; k += 3) {
      const int tw = k * 16;
      const int need = (tw + 17 > 257) ? 257 : (tw + 17);
      while (*((volatile int*)&prog) < need) __builtin_amdgcn_s_sleep(32);
      asm volatile("" ::: "memory");

      // Q B-frag: one b64 (slots 8+4lgrp..11+4lgrp; lgrp 2 reads zeros,
      // lgrp 3 guarded to stay in-row -> zero)
      half4 qf = {(_Float16)0.f, (_Float16)0.f, (_Float16)0.f, (_Float16)0.f};
      if (lgrp < 3)
        qf = *reinterpret_cast<const half4*>(
            &kq_l[(tw + lrow + 1) * KQS2 + 8 + 4 * lgrp]);

      f32x4 oa0 = zf, oa1 = zf, oa2 = zf, oa3 = zf;
      float su = 0.f;

#pragma unroll 1
      for (int sb = 0; sb <= tw + 16; sb += 16) {
        // K A-frag: one b64 (slots 4lgrp..4lgrp+3; junk q-slots multiply
        // zero B rows -> annihilate)
        const half4 kf = *reinterpret_cast<const half4*>(
            &kq_l[(sb + lrow) * KQS2 + 4 * lgrp]);

        const f32x4 sc =
            __builtin_amdgcn_mfma_f32_16x16x16f16(kf, qf, zf, 0, 0, 0);

        half4 pa;
#pragma unroll
        for (int r = 0; r < 4; ++r) {
          const int s = sb + 4 * lgrp + r;
          const float p = (s <= tw + lrow + 1) ? __expf(sc[r]) : 0.f;
          su += p;
          pa[r] = (_Float16)p;
        }

        const int vb = sb + 4 * lgrp;
#define PVF(HT, ACC)                                                      \
  {                                                                       \
    const half4 vf = *reinterpret_cast<const half4*>(                     \
        &ctx_lT[(lrow + 16 * HT) * CXS2 + vb]);                           \
    ACC = __builtin_amdgcn_mfma_f32_16x16x16f16(pa, vf, ACC, 0, 0, 0);    \
  }
        PVF(0, oa0) PVF(1, oa1) PVF(2, oa2) PVF(3, oa3)
      }

      su += __shfl_xor(su, 16, 64);
      su += __shfl_xor(su, 32, 64);

#define PTC(r)                                                                 \
  float pt##r##_0 = oa0[r] * wa_0_0 + oa1[r] * wa_0_1 + oa2[r] * wa_0_2 +      \
                    oa3[r] * wa_0_3;                                           \
  float pt##r##_1 = oa0[r] * wa_1_0 + oa1[r] * wa_1_1 + oa2[r] * wa_1_2 +      \
                    oa3[r] * wa_1_3;                                           \
  float pt##r##_2 = oa0[r] * wa_2_0 + oa1[r] * wa_2_1 + oa2[r] * wa_2_2 +      \
                    oa3[r] * wa_2_3;                                           \
  float pt##r##_3 = oa0[r] * wa_3_0 + oa1[r] * wa_3_1 + oa2[r] * wa_3_2 +      \
                    oa3[r] * wa_3_3;
      PTC(0) PTC(1) PTC(2) PTC(3)
#define REDX(v)                 \
  v += __shfl_xor(v, 1, 64);    \
  v += __shfl_xor(v, 2, 64);    \
  v += __shfl_xor(v, 4, 64);    \
  v += __shfl_xor(v, 8, 64);
      REDX(pt0_0) REDX(pt0_1) REDX(pt0_2) REDX(pt0_3)
      REDX(pt1_0) REDX(pt1_1) REDX(pt1_2) REDX(pt1_3)
      REDX(pt2_0) REDX(pt2_1) REDX(pt2_2) REDX(pt2_3)
      REDX(pt3_0) REDX(pt3_1) REDX(pt3_2) REDX(pt3_3)

#define EPI(r)                                                            \
  {                                                                       \
    const float sur = __shfl(su, 4 * lgrp + (r), 64);                     \
    if (lrow == 0) {                                                      \
      const float inv = 1.f / sur;                                        \
      const int t = tw + 4 * lgrp + (r);                                  \
      *reinterpret_cast<float4*>(out + ((size_t)t * BB + b) * AA) =       \
          make_float4(fmaf(pt##r##_0, inv, ba0), fmaf(pt##r##_1, inv, ba1), \
                      fmaf(pt##r##_2, inv, ba2), fmaf(pt##r##_3, inv, ba3)); \
    }                                                                     \
  }
      EPI(0) EPI(1) EPI(2) EPI(3)
    }
  }
}

extern "C" void kernel_launch(void* const* d_in, const int* in_sizes, int n_in,
                              void* d_out, int out_size, void* d_ws,
                              size_t ws_size, hipStream_t stream) {
  const float* x = (const float*)d_in[0];
  const float* W_in = (const float*)d_in[1];
  const float* b_in = (const float*)d_in[2];
  const float* W_ctx = (const float*)d_in[3];
  const float* b_ctx = (const float*)d_in[4];
  const float* W_key = (const float*)d_in[5];
  const float* b_key = (const float*)d_in[6];
  const float* W_q = (const float*)d_in[7];
  const float* b_q = (const float*)d_in[8];
  const float* fc = (const float*)d_in[9];
  const float* W_act = (const float*)d_in[10];
  const float* b_act = (const float*)d_in[11];
  float* out = (float*)d_out;
  float* ws = (float*)d_ws;

  float* WHT = ws;                                 // 50*52
  float* WK2T = ws + 4096;                         // 50*64
  float* bias2 = ws + 8128;                        // 64
  float* g = ws + 8192;                            // 131072*52
  // total ~27 MB

  hipLaunchKernelGGL(k0_prep, dim3(26), dim3(256), 0, stream, W_in, W_ctx,
                     W_key, W_q, b_key, b_q, WHT, WK2T, bias2);
  hipLaunchKernelGGL(k1_mfma, dim3(512), dim3(256), 0, stream, x, W_in, WHT,
                     b_in, b_ctx, g);
  hipLaunchKernelGGL(k23_fused, dim3(512), dim3(256), 0, stream, g, WK2T,
                     bias2, fc, W_act, b_act, out);
}